// Round 1
// 576.221 us; speedup vs baseline: 1.1457x; 1.1457x over previous
//
#include <hip/hip_runtime.h>
#include <hip/hip_bf16.h>

// GAT 2-layer forward for MI355X (gfx950). Round 4: GEMM moved to the matrix
// pipe via fp16 3-product split (Xh@Wh + Xl@Wh + Xh@Wl), mfma_f32_16x16x32_f16.
// Everything else (CSR build, edge pass, wave-per-dst aggregate) unchanged.
//
// d_out (floats, return order):
//   [0, N*128)            temp = h2 flat
//   [N*128, N*128+4*N*32) heads h2[:,i]
//   [2*N*128, +E*4)       e1
//   [+E]                  atten0
//   [+E]                  atten1
//
// Workspace: feat(N*128) | h1(N*128) | exw(E*4, CSR order) | el(N*4) | er(N*4) |
//            ints: deg(N) row_off(N) cursor(N) csr_src(E) pos(E) bsums(256)
// The fp16 split weights (256KB max) live at the head of the exw region, which
// is dead between aggregate<L> and the next edge_kernel.

typedef _Float16 f16;
typedef _Float16 f16x8 __attribute__((ext_vector_type(8)));
typedef float f32x4 __attribute__((ext_vector_type(4)));

// ---------------- W split: W[K][128] f32 -> Wth/Wtl [128][K] fp16 ------------
__global__ void wsplit(const float* __restrict__ W, f16* __restrict__ Wth,
                       f16* __restrict__ Wtl, int K) {
    int i = blockIdx.x * blockDim.x + threadIdx.x;
    if (i >= K * 128) return;
    int k = i >> 7, c = i & 127;
    float v = W[i];
    f16 h = (f16)v;
    f16 l = (f16)(v - (float)h);
    Wth[(size_t)c * K + k] = h;
    Wtl[(size_t)c * K + k] = l;
}

// ---------------- GEMM: Y[nrows,128] = X[nrows,K] @ W[K,128] (fp16x3 MFMA) ---
// Block: 256 threads = 4 waves; tile 128 rows x 128 cols; K-chunk 32.
// A fragment (16x16x32): lane l holds A[row=l&15][k=8*(l>>4)+i], i=0..7.
// B fragment:            lane l holds B[k=8*(l>>4)+i][col=l&15].
// D: lane l reg r -> D[row=4*(l>>4)+r][col=l&15].
__global__ __launch_bounds__(256, 2) void gemm_mfma(
        const float* __restrict__ X, const f16* __restrict__ Wth,
        const f16* __restrict__ Wtl, float* __restrict__ Y,
        int nrows, int K) {
    constexpr int STR = 40;  // fp16 stride: 80B rows -> 2-way bank alias (free)
    __shared__ f16 ash[128 * STR];
    __shared__ f16 asl[128 * STR];
    __shared__ f16 bsh[128 * STR];
    __shared__ f16 bsl[128 * STR];
    const int t    = threadIdx.x;
    const int wave = t >> 6;
    const int lane = t & 63;
    const int lr   = lane & 15;   // frag row (A) / col (B,D)
    const int kg   = lane >> 4;   // k-group 0..3
    const int row0 = blockIdx.x * 128;

    const int sr  = t >> 1;        // staging row/col 0..127
    const int sko = (t & 1) * 16;  // staging k offset 0/16
    int gr = row0 + sr; if (gr >= nrows) gr = nrows - 1;

    f32x4 acc[2][8];
    #pragma unroll
    for (int i = 0; i < 2; ++i)
        #pragma unroll
        for (int j = 0; j < 8; ++j) acc[i][j] = (f32x4){0.f, 0.f, 0.f, 0.f};

    for (int k0 = 0; k0 < K; k0 += 32) {
        // ---- stage A: X[row0..row0+127][k0..k0+31] f32 -> fp16 hi/lo ----
        {
            const float* xp = X + (size_t)gr * K + k0 + sko;
            float4 v0 = *(const float4*)(xp + 0);
            float4 v1 = *(const float4*)(xp + 4);
            float4 v2 = *(const float4*)(xp + 8);
            float4 v3 = *(const float4*)(xp + 12);
            float vv[16] = {v0.x, v0.y, v0.z, v0.w, v1.x, v1.y, v1.z, v1.w,
                            v2.x, v2.y, v2.z, v2.w, v3.x, v3.y, v3.z, v3.w};
            f16x8 H0, H1, L0, L1;
            #pragma unroll
            for (int i = 0; i < 8; ++i) {
                f16 h0 = (f16)vv[i];
                H0[i] = h0;
                L0[i] = (f16)(vv[i] - (float)h0);
                f16 h1 = (f16)vv[i + 8];
                H1[i] = h1;
                L1[i] = (f16)(vv[i + 8] - (float)h1);
            }
            *(f16x8*)&ash[sr * STR + sko]     = H0;
            *(f16x8*)&ash[sr * STR + sko + 8] = H1;
            *(f16x8*)&asl[sr * STR + sko]     = L0;
            *(f16x8*)&asl[sr * STR + sko + 8] = L1;
        }
        // ---- stage B: Wth/Wtl[col][k0..k0+31] fp16 ----
        {
            const f16* bph = Wth + (size_t)sr * K + k0 + sko;
            const f16* bpl = Wtl + (size_t)sr * K + k0 + sko;
            f16x8 b0 = *(const f16x8*)(bph);
            f16x8 b1 = *(const f16x8*)(bph + 8);
            f16x8 b2 = *(const f16x8*)(bpl);
            f16x8 b3 = *(const f16x8*)(bpl + 8);
            *(f16x8*)&bsh[sr * STR + sko]     = b0;
            *(f16x8*)&bsh[sr * STR + sko + 8] = b1;
            *(f16x8*)&bsl[sr * STR + sko]     = b2;
            *(f16x8*)&bsl[sr * STR + sko + 8] = b3;
        }
        __syncthreads();

        // ---- fragments ----
        const int arow = wave * 32 + lr;
        f16x8 ah0 = *(const f16x8*)&ash[arow * STR + kg * 8];
        f16x8 ah1 = *(const f16x8*)&ash[(arow + 16) * STR + kg * 8];
        f16x8 al0 = *(const f16x8*)&asl[arow * STR + kg * 8];
        f16x8 al1 = *(const f16x8*)&asl[(arow + 16) * STR + kg * 8];
        f16x8 bh[8];
        #pragma unroll
        for (int cb = 0; cb < 8; ++cb)
            bh[cb] = *(const f16x8*)&bsh[(cb * 16 + lr) * STR + kg * 8];

        // pass 1: Xh @ Wh
        #pragma unroll
        for (int cb = 0; cb < 8; ++cb) {
            acc[0][cb] = __builtin_amdgcn_mfma_f32_16x16x32_f16(ah0, bh[cb], acc[0][cb], 0, 0, 0);
            acc[1][cb] = __builtin_amdgcn_mfma_f32_16x16x32_f16(ah1, bh[cb], acc[1][cb], 0, 0, 0);
        }
        // pass 2: Xl @ Wh
        #pragma unroll
        for (int cb = 0; cb < 8; ++cb) {
            acc[0][cb] = __builtin_amdgcn_mfma_f32_16x16x32_f16(al0, bh[cb], acc[0][cb], 0, 0, 0);
            acc[1][cb] = __builtin_amdgcn_mfma_f32_16x16x32_f16(al1, bh[cb], acc[1][cb], 0, 0, 0);
        }
        // pass 3: Xh @ Wl (Wl streamed to keep VGPR down)
        #pragma unroll
        for (int cb = 0; cb < 8; ++cb) {
            f16x8 bl = *(const f16x8*)&bsl[(cb * 16 + lr) * STR + kg * 8];
            acc[0][cb] = __builtin_amdgcn_mfma_f32_16x16x32_f16(ah0, bl, acc[0][cb], 0, 0, 0);
            acc[1][cb] = __builtin_amdgcn_mfma_f32_16x16x32_f16(ah1, bl, acc[1][cb], 0, 0, 0);
        }
        __syncthreads();
    }

    // ---- epilogue: D[row=4*kg+r][col=lr] per (rowblk, colblk) ----
    #pragma unroll
    for (int rb = 0; rb < 2; ++rb) {
        int rbase = row0 + wave * 32 + rb * 16 + kg * 4;
        #pragma unroll
        for (int r = 0; r < 4; ++r) {
            int grow = rbase + r;
            if (grow < nrows) {
                float* yp = Y + (size_t)grow * 128 + lr;
                #pragma unroll
                for (int cb = 0; cb < 8; ++cb) yp[cb * 16] = acc[rb][cb][r];
            }
        }
    }
}

// ---------------- el/er: [N,4] head-wise dot with al/ar [4,32] ----------------
__global__ void eler_kernel(const float* __restrict__ feat,
                            const float* __restrict__ al,
                            const float* __restrict__ ar,
                            float* __restrict__ el, float* __restrict__ er, int n) {
    int i = blockIdx.x * blockDim.x + threadIdx.x;
    if (i >= n * 4) return;
    int node = i >> 2, h = i & 3;
    const float* f   = feat + (size_t)node * 128 + h * 32;
    const float* alh = al + h * 32;
    const float* arh = ar + h * 32;
    float sl = 0.0f, sr = 0.0f;
    #pragma unroll
    for (int d = 0; d < 32; d += 4) {
        float4 fv  = *(const float4*)(f + d);
        float4 alv = *(const float4*)(alh + d);
        float4 arv = *(const float4*)(arh + d);
        sl += fv.x * alv.x + fv.y * alv.y + fv.z * alv.z + fv.w * alv.w;
        sr += fv.x * arv.x + fv.y * arv.y + fv.z * arv.z + fv.w * arv.w;
    }
    el[i] = sl; er[i] = sr;
}

// ---------------- CSR build ----------------
__global__ void count_deg(const int* __restrict__ dsts, int* __restrict__ deg, int E) {
    int e = blockIdx.x * blockDim.x + threadIdx.x;
    if (e < E) atomicAdd(&deg[dsts[e]], 1);
}

__global__ __launch_bounds__(256) void scan_block(const int* __restrict__ deg,
                                                  int* __restrict__ excl,
                                                  int* __restrict__ bsums, int n) {
    __shared__ int wsums[4];
    int t = threadIdx.x;
    int base = blockIdx.x * 1024;
    int idx = base + t * 4;
    int v[4];
    #pragma unroll
    for (int i = 0; i < 4; ++i) v[i] = (idx + i < n) ? deg[idx + i] : 0;
    int tsum = v[0] + v[1] + v[2] + v[3];
    int lane = t & 63, wid = t >> 6;
    int incl = tsum;
    #pragma unroll
    for (int off = 1; off < 64; off <<= 1) {
        int u = __shfl_up(incl, off, 64);
        if (lane >= off) incl += u;
    }
    if (lane == 63) wsums[wid] = incl;
    __syncthreads();
    if (t == 0) {
        int s = 0;
        #pragma unroll
        for (int w = 0; w < 4; ++w) { int x = wsums[w]; wsums[w] = s; s += x; }
    }
    __syncthreads();
    int ex = incl - tsum + wsums[wid];
    int run = ex;
    #pragma unroll
    for (int i = 0; i < 4; ++i) { if (idx + i < n) excl[idx + i] = run; run += v[i]; }
    if (t == 255) bsums[blockIdx.x] = ex + tsum;
}

__global__ __launch_bounds__(256) void scan_sums(int* __restrict__ bs, int nb) {
    __shared__ int wsums[4];
    int t = threadIdx.x;
    int v = (t < nb) ? bs[t] : 0;
    int lane = t & 63, wid = t >> 6;
    int incl = v;
    #pragma unroll
    for (int off = 1; off < 64; off <<= 1) {
        int u = __shfl_up(incl, off, 64);
        if (lane >= off) incl += u;
    }
    if (lane == 63) wsums[wid] = incl;
    __syncthreads();
    if (t == 0) {
        int s = 0;
        #pragma unroll
        for (int w = 0; w < 4; ++w) { int x = wsums[w]; wsums[w] = s; s += x; }
    }
    __syncthreads();
    if (t < nb) bs[t] = incl - v + wsums[wid];
}

__global__ void scan_finalize(int* __restrict__ row_off, const int* __restrict__ bsums,
                              int* __restrict__ cursor, int n) {
    int i = blockIdx.x * blockDim.x + threadIdx.x;
    if (i < n) {
        int v = row_off[i] + bsums[i >> 10];
        row_off[i] = v;
        cursor[i]  = v;
    }
}

__global__ void fill_csr(const int* __restrict__ dsts, const int* __restrict__ srcs,
                         int* __restrict__ cursor, int* __restrict__ csr_src,
                         int* __restrict__ pos, int E) {
    int e = blockIdx.x * blockDim.x + threadIdx.x;
    if (e < E) {
        int p = atomicAdd(&cursor[dsts[e]], 1);
        csr_src[p] = srcs[e];
        pos[e] = p;
    }
}

// ---------------- edge pass: scores, exp (scattered to CSR order) -----------
__global__ void edge_kernel(const int* __restrict__ srcs, const int* __restrict__ dsts,
                            const int* __restrict__ pos,
                            const float* __restrict__ el, const float* __restrict__ er,
                            float* __restrict__ exw,        // [E,4] CSR order
                            float* __restrict__ e_out,      // nullptr (layer0) or [E,4]
                            float* __restrict__ atten_out,  // [E]
                            int E) {
    int e = blockIdx.x * blockDim.x + threadIdx.x;
    if (e >= E) return;
    int s = srcs[e], d = dsts[e];
    float4 elv = *(const float4*)(el + 4 * (size_t)s);
    float4 erv = *(const float4*)(er + 4 * (size_t)d);
    float v[4] = {elv.x + erv.x, elv.y + erv.y, elv.z + erv.z, elv.w + erv.w};
    float ex[4];
    float sum = 0.0f;
    #pragma unroll
    for (int h = 0; h < 4; ++h) {
        float lr = v[h] > 0.0f ? v[h] : 0.2f * v[h];
        v[h] = lr;
        sum += lr;
        ex[h] = __expf(lr);
    }
    int p = pos[e];
    *(float4*)(exw + 4 * (size_t)p) = make_float4(ex[0], ex[1], ex[2], ex[3]);
    if (e_out) *(float4*)(e_out + 4 * (size_t)e) = make_float4(v[0], v[1], v[2], v[3]);
    atten_out[e] = sum * 0.25f;
}

// ---------------- gather aggregation: one wave per dst node -----------------
// Single pass: acc = sum(exp * feat[src]); dh = sum(exp); result = acc/dh.
// srcs preloaded one-per-lane, broadcast via __shfl (v_readlane) so all feat
// row addresses are known up front -> deep MLP.
template <int LAYER>
__global__ __launch_bounds__(256) void aggregate(const int* __restrict__ row_off,
                                                 const int* __restrict__ deg,
                                                 const int* __restrict__ csr_src,
                                                 const float* __restrict__ exw,
                                                 const float* __restrict__ feat,
                                                 const float* __restrict__ resid,
                                                 float* __restrict__ out0,
                                                 float* __restrict__ heads,
                                                 int N) {
    int wave = (blockIdx.x * 256 + threadIdx.x) >> 6;
    if (wave >= N) return;
    int lane = threadIdx.x & 63;
    int start = row_off[wave];
    int dc    = deg[wave];
    int h  = lane >> 4;
    int c0 = lane * 2;

    float dh = 0.0f;
    float2 acc = make_float2(0.0f, 0.0f);

    for (int cs = 0; cs < dc; cs += 64) {
        int act = dc - cs; if (act > 64) act = 64;
        int sl = (lane < act) ? csr_src[start + cs + lane] : 0;
        const float* wp = exw + 4 * (size_t)(start + cs) + h;
        int i = 0;
        for (; i + 4 <= act; i += 4) {
            int s0 = __shfl(sl, i);
            int s1 = __shfl(sl, i + 1);
            int s2 = __shfl(sl, i + 2);
            int s3 = __shfl(sl, i + 3);
            float w0 = wp[4 * i];
            float w1 = wp[4 * (i + 1)];
            float w2 = wp[4 * (i + 2)];
            float w3 = wp[4 * (i + 3)];
            float2 f0 = *(const float2*)(feat + 128 * (size_t)s0 + c0);
            float2 f1 = *(const float2*)(feat + 128 * (size_t)s1 + c0);
            float2 f2 = *(const float2*)(feat + 128 * (size_t)s2 + c0);
            float2 f3 = *(const float2*)(feat + 128 * (size_t)s3 + c0);
            acc.x += w0 * f0.x; acc.y += w0 * f0.y;
            acc.x += w1 * f1.x; acc.y += w1 * f1.y;
            acc.x += w2 * f2.x; acc.y += w2 * f2.y;
            acc.x += w3 * f3.x; acc.y += w3 * f3.y;
            dh += w0 + w1 + w2 + w3;
        }
        for (; i < act; ++i) {
            int s = __shfl(sl, i);
            float w = wp[4 * i];
            float2 f = *(const float2*)(feat + 128 * (size_t)s + c0);
            acc.x += w * f.x; acc.y += w * f.y;
            dh += w;
        }
    }

    float inv = (dc > 0) ? 1.0f / dh : 0.0f;
    acc.x *= inv; acc.y *= inv;
    size_t o = 128 * (size_t)wave + c0;
    if (LAYER == 1) { acc.x += resid[o]; acc.y += resid[o + 1]; }
    acc.x = acc.x > 0.0f ? acc.x : __expf(acc.x) - 1.0f;
    acc.y = acc.y > 0.0f ? acc.y : __expf(acc.y) - 1.0f;
    *(float2*)(out0 + o) = acc;
    if (LAYER == 1) {
        *(float2*)(heads + (size_t)h * N * 32 + (size_t)wave * 32 + (c0 & 31)) = acc;
    }
}

extern "C" void kernel_launch(void* const* d_in, const int* in_sizes, int n_in,
                              void* d_out, int out_size, void* d_ws, size_t ws_size,
                              hipStream_t stream) {
    const float* x   = (const float*)d_in[0];
    const int*   ei  = (const int*)d_in[1];
    const float* W0  = (const float*)d_in[2];
    const float* al0 = (const float*)d_in[3];
    const float* ar0 = (const float*)d_in[4];
    const float* W1  = (const float*)d_in[5];
    const float* al1 = (const float*)d_in[6];
    const float* ar1 = (const float*)d_in[7];

    const int N = in_sizes[0] / 256;     // 100000
    const int E = in_sizes[1] / 2;       // 800000
    const size_t NF = (size_t)N * 128;

    const int* srcs = ei;
    const int* dsts = ei + E;

    float* out = (float*)d_out;
    float* ws  = (float*)d_ws;
    float* feat = ws;                                    // N*128
    float* h1   = ws + NF;                               // N*128
    float* exw  = ws + 2 * NF;                           // E*4 (CSR order)
    float* el   = exw + (size_t)E * 4;                   // N*4
    float* er   = el + (size_t)N * 4;                    // N*4
    int*   ints    = (int*)(er + (size_t)N * 4);
    int*   deg     = ints;                               // N
    int*   row_off = deg + N;                            // N
    int*   cursor  = row_off + N;                        // N
    int*   csr_src = cursor + N;                         // E
    int*   pos     = csr_src + E;                        // E
    int*   bsums   = pos + E;                            // <=256

    float* heads      = out + NF;
    float* e1_out     = out + 2 * NF;
    float* atten0_out = e1_out + (size_t)E * 4;
    float* atten1_out = atten0_out + E;

    // fp16 split weights live at the head of the exw region (dead there:
    // wsplit+gemm run before edge_kernel rewrites exw each layer).
    f16* wth  = (f16*)exw;
    f16* wtl0 = wth + (size_t)128 * 256;
    f16* wtl1 = wth + (size_t)128 * 128;

    // ---- CSR build (int atomics only) ----
    hipMemsetAsync(deg, 0, (size_t)N * sizeof(int), stream);
    count_deg<<<(E + 255) / 256, 256, 0, stream>>>(dsts, deg, E);
    int nb = (N + 1023) / 1024;
    scan_block<<<nb, 256, 0, stream>>>(deg, row_off, bsums, N);
    scan_sums<<<1, 256, 0, stream>>>(bsums, nb);
    scan_finalize<<<(N + 255) / 256, 256, 0, stream>>>(row_off, bsums, cursor, N);
    fill_csr<<<(E + 255) / 256, 256, 0, stream>>>(dsts, srcs, cursor, csr_src, pos, E);

    const int gemm_blocks = (N + 127) / 128;
    const int agg_blocks  = (N + 3) / 4;

    // ---- layer 0 ----
    wsplit<<<(256 * 128 + 255) / 256, 256, 0, stream>>>(W0, wth, wtl0, 256);
    gemm_mfma<<<gemm_blocks, 256, 0, stream>>>(x, wth, wtl0, feat, N, 256);
    eler_kernel<<<(N * 4 + 255) / 256, 256, 0, stream>>>(feat, al0, ar0, el, er, N);
    edge_kernel<<<(E + 255) / 256, 256, 0, stream>>>(srcs, dsts, pos, el, er, exw,
                                                     nullptr, atten0_out, E);
    aggregate<0><<<agg_blocks, 256, 0, stream>>>(row_off, deg, csr_src, exw, feat,
                                                 nullptr, h1, nullptr, N);

    // ---- layer 1 ----
    wsplit<<<(128 * 128 + 255) / 256, 256, 0, stream>>>(W1, wth, wtl1, 128);
    gemm_mfma<<<gemm_blocks, 256, 0, stream>>>(h1, wth, wtl1, feat, N, 128);
    eler_kernel<<<(N * 4 + 255) / 256, 256, 0, stream>>>(feat, al1, ar1, el, er, N);
    edge_kernel<<<(E + 255) / 256, 256, 0, stream>>>(srcs, dsts, pos, el, er, exw,
                                                     e1_out, atten1_out, E);
    aggregate<1><<<agg_blocks, 256, 0, stream>>>(row_off, deg, csr_src, exw, feat,
                                                 h1, out, heads, N);
}

// Round 2
// 522.354 us; speedup vs baseline: 1.2638x; 1.1031x over previous
//
#include <hip/hip_runtime.h>
#include <hip/hip_bf16.h>

// GAT 2-layer forward for MI355X (gfx950). Round 5: feat stored fp16-only.
// - gemm_mfma (fp16 3-product split) now writes packed f16x8 rows via a
//   permuted B-staging so each lane owns 8 contiguous output cols.
// - aggregate gathers f16x8 (16B/lane, 4 rows per wave-load) with
//   quarter-wave edge parallelism + shfl_xor cross-quarter reduction.
// - eler reads fp16 feat.
//
// d_out (floats, return order):
//   [0, N*128)            temp = h2 flat
//   [N*128, N*128+4*N*32) heads h2[:,i]
//   [2*N*128, +E*4)       e1
//   [+E]                  atten0
//   [+E]                  atten1
//
// Workspace: feat16(N*128 f16, in old feat slot) | h1(N*128 f32) |
//            exw(E*4, CSR order) | el(N*4) | er(N*4) |
//            ints: deg(N) row_off(N) cursor(N) csr_src(E) pos(E) bsums(256)
// fp16 split weights live at the head of the exw region (dead there).

typedef _Float16 f16;
typedef _Float16 f16x8 __attribute__((ext_vector_type(8)));
typedef float f32x4 __attribute__((ext_vector_type(4)));

// ---------------- W split: W[K][128] f32 -> Wth/Wtl [128][K] fp16 ------------
__global__ void wsplit(const float* __restrict__ W, f16* __restrict__ Wth,
                       f16* __restrict__ Wtl, int K) {
    int i = blockIdx.x * blockDim.x + threadIdx.x;
    if (i >= K * 128) return;
    int k = i >> 7, c = i & 127;
    float v = W[i];
    f16 h = (f16)v;
    f16 l = (f16)(v - (float)h);
    Wth[(size_t)c * K + k] = h;
    Wtl[(size_t)c * K + k] = l;
}

// ---------------- GEMM: Y16[nrows,128] = fp16(X[nrows,K] @ W[K,128]) ---------
// fp16x3 split on mfma_f32_16x16x32_f16. Block 256 = 4 waves, tile 128x128.
// B cols staged permuted: staged s = ((p&7)<<4)|(p>>3)  <=>  p = lr*8 + cb,
// so lane (lr) owns 8 contiguous physical cols -> one f16x8 store per row.
__global__ __launch_bounds__(256, 2) void gemm_mfma(
        const float* __restrict__ X, const f16* __restrict__ Wth,
        const f16* __restrict__ Wtl, f16* __restrict__ Y16,
        int nrows, int K) {
    constexpr int STR = 40;  // fp16 stride: 80B rows -> 2-way bank alias (free)
    __shared__ f16 ash[128 * STR];
    __shared__ f16 asl[128 * STR];
    __shared__ f16 bsh[128 * STR];
    __shared__ f16 bsl[128 * STR];
    const int t    = threadIdx.x;
    const int wave = t >> 6;
    const int lane = t & 63;
    const int lr   = lane & 15;   // frag row (A) / col (B,D)
    const int kg   = lane >> 4;   // k-group 0..3
    const int row0 = blockIdx.x * 128;

    const int sr  = t >> 1;        // staging row (A) / physical col (B) 0..127
    const int sko = (t & 1) * 16;  // staging k offset 0/16
    const int ps  = ((sr & 7) << 4) | (sr >> 3);  // permuted staged B col
    int gr = row0 + sr; if (gr >= nrows) gr = nrows - 1;

    f32x4 acc[2][8];
    #pragma unroll
    for (int i = 0; i < 2; ++i)
        #pragma unroll
        for (int j = 0; j < 8; ++j) acc[i][j] = (f32x4){0.f, 0.f, 0.f, 0.f};

    for (int k0 = 0; k0 < K; k0 += 32) {
        // ---- stage A: X[row0..row0+127][k0..k0+31] f32 -> fp16 hi/lo ----
        {
            const float* xp = X + (size_t)gr * K + k0 + sko;
            float4 v0 = *(const float4*)(xp + 0);
            float4 v1 = *(const float4*)(xp + 4);
            float4 v2 = *(const float4*)(xp + 8);
            float4 v3 = *(const float4*)(xp + 12);
            float vv[16] = {v0.x, v0.y, v0.z, v0.w, v1.x, v1.y, v1.z, v1.w,
                            v2.x, v2.y, v2.z, v2.w, v3.x, v3.y, v3.z, v3.w};
            f16x8 H0, H1, L0, L1;
            #pragma unroll
            for (int i = 0; i < 8; ++i) {
                f16 h0 = (f16)vv[i];
                H0[i] = h0;
                L0[i] = (f16)(vv[i] - (float)h0);
                f16 h1 = (f16)vv[i + 8];
                H1[i] = h1;
                L1[i] = (f16)(vv[i + 8] - (float)h1);
            }
            *(f16x8*)&ash[sr * STR + sko]     = H0;
            *(f16x8*)&ash[sr * STR + sko + 8] = H1;
            *(f16x8*)&asl[sr * STR + sko]     = L0;
            *(f16x8*)&asl[sr * STR + sko + 8] = L1;
        }
        // ---- stage B (permuted): Wth/Wtl[physcol sr][k0..k0+31] fp16 ----
        {
            const f16* bph = Wth + (size_t)sr * K + k0 + sko;
            const f16* bpl = Wtl + (size_t)sr * K + k0 + sko;
            f16x8 b0 = *(const f16x8*)(bph);
            f16x8 b1 = *(const f16x8*)(bph + 8);
            f16x8 b2 = *(const f16x8*)(bpl);
            f16x8 b3 = *(const f16x8*)(bpl + 8);
            *(f16x8*)&bsh[ps * STR + sko]     = b0;
            *(f16x8*)&bsh[ps * STR + sko + 8] = b1;
            *(f16x8*)&bsl[ps * STR + sko]     = b2;
            *(f16x8*)&bsl[ps * STR + sko + 8] = b3;
        }
        __syncthreads();

        // ---- fragments ----
        const int arow = wave * 32 + lr;
        f16x8 ah0 = *(const f16x8*)&ash[arow * STR + kg * 8];
        f16x8 ah1 = *(const f16x8*)&ash[(arow + 16) * STR + kg * 8];
        f16x8 al0 = *(const f16x8*)&asl[arow * STR + kg * 8];
        f16x8 al1 = *(const f16x8*)&asl[(arow + 16) * STR + kg * 8];
        f16x8 bh[8];
        #pragma unroll
        for (int cb = 0; cb < 8; ++cb)
            bh[cb] = *(const f16x8*)&bsh[(cb * 16 + lr) * STR + kg * 8];

        // pass 1: Xh @ Wh
        #pragma unroll
        for (int cb = 0; cb < 8; ++cb) {
            acc[0][cb] = __builtin_amdgcn_mfma_f32_16x16x32_f16(ah0, bh[cb], acc[0][cb], 0, 0, 0);
            acc[1][cb] = __builtin_amdgcn_mfma_f32_16x16x32_f16(ah1, bh[cb], acc[1][cb], 0, 0, 0);
        }
        // pass 2: Xl @ Wh
        #pragma unroll
        for (int cb = 0; cb < 8; ++cb) {
            acc[0][cb] = __builtin_amdgcn_mfma_f32_16x16x32_f16(al0, bh[cb], acc[0][cb], 0, 0, 0);
            acc[1][cb] = __builtin_amdgcn_mfma_f32_16x16x32_f16(al1, bh[cb], acc[1][cb], 0, 0, 0);
        }
        // pass 3: Xh @ Wl (Wl streamed to keep VGPR down)
        #pragma unroll
        for (int cb = 0; cb < 8; ++cb) {
            f16x8 bl = *(const f16x8*)&bsl[(cb * 16 + lr) * STR + kg * 8];
            acc[0][cb] = __builtin_amdgcn_mfma_f32_16x16x32_f16(ah0, bl, acc[0][cb], 0, 0, 0);
            acc[1][cb] = __builtin_amdgcn_mfma_f32_16x16x32_f16(ah1, bl, acc[1][cb], 0, 0, 0);
        }
        __syncthreads();
    }

    // ---- epilogue: lane owns physical cols lr*8..lr*8+7 of its rows ----
    #pragma unroll
    for (int rb = 0; rb < 2; ++rb) {
        int rbase = row0 + wave * 32 + rb * 16 + kg * 4;
        #pragma unroll
        for (int r = 0; r < 4; ++r) {
            int grow = rbase + r;
            if (grow < nrows) {
                f16x8 hv;
                #pragma unroll
                for (int cb = 0; cb < 8; ++cb) hv[cb] = (f16)acc[rb][cb][r];
                *(f16x8*)(Y16 + (size_t)grow * 128 + lr * 8) = hv;
            }
        }
    }
}

// ---------------- el/er: [N,4] head-wise dot with al/ar [4,32] (fp16 feat) ---
__global__ void eler_kernel(const f16* __restrict__ feat16,
                            const float* __restrict__ al,
                            const float* __restrict__ ar,
                            float* __restrict__ el, float* __restrict__ er, int n) {
    int i = blockIdx.x * blockDim.x + threadIdx.x;
    if (i >= n * 4) return;
    int node = i >> 2, h = i & 3;
    const f16* f     = feat16 + (size_t)node * 128 + h * 32;
    const float* alh = al + h * 32;
    const float* arh = ar + h * 32;
    float sl = 0.0f, sr = 0.0f;
    #pragma unroll
    for (int d = 0; d < 32; d += 8) {
        f16x8 fv = *(const f16x8*)(f + d);
        float4 a0 = *(const float4*)(alh + d);
        float4 a1 = *(const float4*)(alh + d + 4);
        float4 r0 = *(const float4*)(arh + d);
        float4 r1 = *(const float4*)(arh + d + 4);
        sl += (float)fv[0] * a0.x + (float)fv[1] * a0.y + (float)fv[2] * a0.z +
              (float)fv[3] * a0.w + (float)fv[4] * a1.x + (float)fv[5] * a1.y +
              (float)fv[6] * a1.z + (float)fv[7] * a1.w;
        sr += (float)fv[0] * r0.x + (float)fv[1] * r0.y + (float)fv[2] * r0.z +
              (float)fv[3] * r0.w + (float)fv[4] * r1.x + (float)fv[5] * r1.y +
              (float)fv[6] * r1.z + (float)fv[7] * r1.w;
    }
    el[i] = sl; er[i] = sr;
}

// ---------------- CSR build ----------------
__global__ void count_deg(const int* __restrict__ dsts, int* __restrict__ deg, int E) {
    int e = blockIdx.x * blockDim.x + threadIdx.x;
    if (e < E) atomicAdd(&deg[dsts[e]], 1);
}

__global__ __launch_bounds__(256) void scan_block(const int* __restrict__ deg,
                                                  int* __restrict__ excl,
                                                  int* __restrict__ bsums, int n) {
    __shared__ int wsums[4];
    int t = threadIdx.x;
    int base = blockIdx.x * 1024;
    int idx = base + t * 4;
    int v[4];
    #pragma unroll
    for (int i = 0; i < 4; ++i) v[i] = (idx + i < n) ? deg[idx + i] : 0;
    int tsum = v[0] + v[1] + v[2] + v[3];
    int lane = t & 63, wid = t >> 6;
    int incl = tsum;
    #pragma unroll
    for (int off = 1; off < 64; off <<= 1) {
        int u = __shfl_up(incl, off, 64);
        if (lane >= off) incl += u;
    }
    if (lane == 63) wsums[wid] = incl;
    __syncthreads();
    if (t == 0) {
        int s = 0;
        #pragma unroll
        for (int w = 0; w < 4; ++w) { int x = wsums[w]; wsums[w] = s; s += x; }
    }
    __syncthreads();
    int ex = incl - tsum + wsums[wid];
    int run = ex;
    #pragma unroll
    for (int i = 0; i < 4; ++i) { if (idx + i < n) excl[idx + i] = run; run += v[i]; }
    if (t == 255) bsums[blockIdx.x] = ex + tsum;
}

__global__ __launch_bounds__(256) void scan_sums(int* __restrict__ bs, int nb) {
    __shared__ int wsums[4];
    int t = threadIdx.x;
    int v = (t < nb) ? bs[t] : 0;
    int lane = t & 63, wid = t >> 6;
    int incl = v;
    #pragma unroll
    for (int off = 1; off < 64; off <<= 1) {
        int u = __shfl_up(incl, off, 64);
        if (lane >= off) incl += u;
    }
    if (lane == 63) wsums[wid] = incl;
    __syncthreads();
    if (t == 0) {
        int s = 0;
        #pragma unroll
        for (int w = 0; w < 4; ++w) { int x = wsums[w]; wsums[w] = s; s += x; }
    }
    __syncthreads();
    if (t < nb) bs[t] = incl - v + wsums[wid];
}

__global__ void scan_finalize(int* __restrict__ row_off, const int* __restrict__ bsums,
                              int* __restrict__ cursor, int n) {
    int i = blockIdx.x * blockDim.x + threadIdx.x;
    if (i < n) {
        int v = row_off[i] + bsums[i >> 10];
        row_off[i] = v;
        cursor[i]  = v;
    }
}

__global__ void fill_csr(const int* __restrict__ dsts, const int* __restrict__ srcs,
                         int* __restrict__ cursor, int* __restrict__ csr_src,
                         int* __restrict__ pos, int E) {
    int e = blockIdx.x * blockDim.x + threadIdx.x;
    if (e < E) {
        int p = atomicAdd(&cursor[dsts[e]], 1);
        csr_src[p] = srcs[e];
        pos[e] = p;
    }
}

// ---------------- edge pass: scores, exp (scattered to CSR order) -----------
__global__ void edge_kernel(const int* __restrict__ srcs, const int* __restrict__ dsts,
                            const int* __restrict__ pos,
                            const float* __restrict__ el, const float* __restrict__ er,
                            float* __restrict__ exw,        // [E,4] CSR order
                            float* __restrict__ e_out,      // nullptr (layer0) or [E,4]
                            float* __restrict__ atten_out,  // [E]
                            int E) {
    int e = blockIdx.x * blockDim.x + threadIdx.x;
    if (e >= E) return;
    int s = srcs[e], d = dsts[e];
    float4 elv = *(const float4*)(el + 4 * (size_t)s);
    float4 erv = *(const float4*)(er + 4 * (size_t)d);
    float v[4] = {elv.x + erv.x, elv.y + erv.y, elv.z + erv.z, elv.w + erv.w};
    float ex[4];
    float sum = 0.0f;
    #pragma unroll
    for (int h = 0; h < 4; ++h) {
        float lr = v[h] > 0.0f ? v[h] : 0.2f * v[h];
        v[h] = lr;
        sum += lr;
        ex[h] = __expf(lr);
    }
    int p = pos[e];
    *(float4*)(exw + 4 * (size_t)p) = make_float4(ex[0], ex[1], ex[2], ex[3]);
    if (e_out) *(float4*)(e_out + 4 * (size_t)e) = make_float4(v[0], v[1], v[2], v[3]);
    atten_out[e] = sum * 0.25f;
}

// ---------------- gather aggregation: one wave per dst node -----------------
// Lane = (quarter q = lane>>4, col-slot sc = lane&15). Quarter q handles edges
// i+q; each lane loads a contiguous f16x8 (16B) of feat16[src] at cols sc*8.
// One wave-load covers 4 rows (1KB). Cross-quarter combine via shfl_xor(16/32).
template <int LAYER>
__global__ __launch_bounds__(256) void aggregate(const int* __restrict__ row_off,
                                                 const int* __restrict__ deg,
                                                 const int* __restrict__ csr_src,
                                                 const float* __restrict__ exw,
                                                 const f16* __restrict__ feat16,
                                                 const float* __restrict__ resid,
                                                 float* __restrict__ out0,
                                                 float* __restrict__ heads,
                                                 int N) {
    int wave = (blockIdx.x * 256 + threadIdx.x) >> 6;
    if (wave >= N) return;
    int lane = threadIdx.x & 63;
    int q  = lane >> 4;          // edge phase 0..3
    int sc = lane & 15;          // col slot: cols sc*8 .. sc*8+7
    int h  = sc >> 2;            // head of these cols
    int start = row_off[wave];
    int dc    = deg[wave];

    float acc[8];
    #pragma unroll
    for (int j = 0; j < 8; ++j) acc[j] = 0.0f;
    float dh = 0.0f;

    for (int cs = 0; cs < dc; cs += 64) {
        int act = dc - cs; if (act > 64) act = 64;
        int sl = (lane < act) ? csr_src[start + cs + lane] : 0;
        const float* wp = exw + 4 * (size_t)(start + cs) + h;
        int i = 0;
        for (; i + 8 <= act; i += 8) {
            int s0 = __shfl(sl, i + q);
            int s1 = __shfl(sl, i + 4 + q);
            float w0 = wp[4 * (i + q)];
            float w1 = wp[4 * (i + 4 + q)];
            f16x8 f0 = *(const f16x8*)(feat16 + 128 * (size_t)s0 + sc * 8);
            f16x8 f1 = *(const f16x8*)(feat16 + 128 * (size_t)s1 + sc * 8);
            #pragma unroll
            for (int j = 0; j < 8; ++j) acc[j] += w0 * (float)f0[j];
            #pragma unroll
            for (int j = 0; j < 8; ++j) acc[j] += w1 * (float)f1[j];
            dh += w0 + w1;
        }
        for (; i < act; i += 4) {
            int e = i + q;
            bool on = e < act;
            int s = __shfl(sl, on ? e : 0);
            float w = on ? wp[4 * e] : 0.0f;
            f16x8 fv = *(const f16x8*)(feat16 + 128 * (size_t)s + sc * 8);
            #pragma unroll
            for (int j = 0; j < 8; ++j) acc[j] += w * (float)fv[j];
            dh += w;
        }
    }

    // combine the 4 quarter-partials (xor16 flips q bit0, xor32 flips q bit1;
    // sc -> cols preserved)
    #pragma unroll
    for (int j = 0; j < 8; ++j) {
        acc[j] += __shfl_xor(acc[j], 16);
        acc[j] += __shfl_xor(acc[j], 32);
    }
    dh += __shfl_xor(dh, 16);
    dh += __shfl_xor(dh, 32);

    float inv = (dc > 0) ? 1.0f / dh : 0.0f;
    // each lane writes cols c0 = sc*8 + q*2, +1 (static-index select, no scratch)
    float ax = (q == 0) ? acc[0] : (q == 1) ? acc[2] : (q == 2) ? acc[4] : acc[6];
    float ay = (q == 0) ? acc[1] : (q == 1) ? acc[3] : (q == 2) ? acc[5] : acc[7];
    ax *= inv; ay *= inv;
    int c0 = sc * 8 + q * 2;
    size_t o = 128 * (size_t)wave + c0;
    if (LAYER == 1) {
        float2 rv = *(const float2*)(resid + o);
        ax += rv.x; ay += rv.y;
    }
    ax = ax > 0.0f ? ax : __expf(ax) - 1.0f;
    ay = ay > 0.0f ? ay : __expf(ay) - 1.0f;
    *(float2*)(out0 + o) = make_float2(ax, ay);
    if (LAYER == 1) {
        *(float2*)(heads + (size_t)h * N * 32 + (size_t)wave * 32 + (c0 & 31)) =
            make_float2(ax, ay);
    }
}

extern "C" void kernel_launch(void* const* d_in, const int* in_sizes, int n_in,
                              void* d_out, int out_size, void* d_ws, size_t ws_size,
                              hipStream_t stream) {
    const float* x   = (const float*)d_in[0];
    const int*   ei  = (const int*)d_in[1];
    const float* W0  = (const float*)d_in[2];
    const float* al0 = (const float*)d_in[3];
    const float* ar0 = (const float*)d_in[4];
    const float* W1  = (const float*)d_in[5];
    const float* al1 = (const float*)d_in[6];
    const float* ar1 = (const float*)d_in[7];

    const int N = in_sizes[0] / 256;     // 100000
    const int E = in_sizes[1] / 2;       // 800000
    const size_t NF = (size_t)N * 128;

    const int* srcs = ei;
    const int* dsts = ei + E;

    float* out = (float*)d_out;
    float* ws  = (float*)d_ws;
    f16*   feat16 = (f16*)ws;                            // N*128 f16 (in feat slot)
    float* h1   = ws + NF;                               // N*128 f32
    float* exw  = ws + 2 * NF;                           // E*4 (CSR order)
    float* el   = exw + (size_t)E * 4;                   // N*4
    float* er   = el + (size_t)N * 4;                    // N*4
    int*   ints    = (int*)(er + (size_t)N * 4);
    int*   deg     = ints;                               // N
    int*   row_off = deg + N;                            // N
    int*   cursor  = row_off + N;                        // N
    int*   csr_src = cursor + N;                         // E
    int*   pos     = csr_src + E;                        // E
    int*   bsums   = pos + E;                            // <=256

    float* heads      = out + NF;
    float* e1_out     = out + 2 * NF;
    float* atten0_out = e1_out + (size_t)E * 4;
    float* atten1_out = atten0_out + E;

    // fp16 split weights live at the head of the exw region (dead there:
    // wsplit+gemm run before edge_kernel rewrites exw each layer).
    f16* wth  = (f16*)exw;
    f16* wtl0 = wth + (size_t)128 * 256;
    f16* wtl1 = wth + (size_t)128 * 128;

    // ---- CSR build (int atomics only) ----
    hipMemsetAsync(deg, 0, (size_t)N * sizeof(int), stream);
    count_deg<<<(E + 255) / 256, 256, 0, stream>>>(dsts, deg, E);
    int nb = (N + 1023) / 1024;
    scan_block<<<nb, 256, 0, stream>>>(deg, row_off, bsums, N);
    scan_sums<<<1, 256, 0, stream>>>(bsums, nb);
    scan_finalize<<<(N + 255) / 256, 256, 0, stream>>>(row_off, bsums, cursor, N);
    fill_csr<<<(E + 255) / 256, 256, 0, stream>>>(dsts, srcs, cursor, csr_src, pos, E);

    const int gemm_blocks = (N + 127) / 128;
    const int agg_blocks  = (N + 3) / 4;

    // ---- layer 0 ----
    wsplit<<<(256 * 128 + 255) / 256, 256, 0, stream>>>(W0, wth, wtl0, 256);
    gemm_mfma<<<gemm_blocks, 256, 0, stream>>>(x, wth, wtl0, feat16, N, 256);
    eler_kernel<<<(N * 4 + 255) / 256, 256, 0, stream>>>(feat16, al0, ar0, el, er, N);
    edge_kernel<<<(E + 255) / 256, 256, 0, stream>>>(srcs, dsts, pos, el, er, exw,
                                                     nullptr, atten0_out, E);
    aggregate<0><<<agg_blocks, 256, 0, stream>>>(row_off, deg, csr_src, exw, feat16,
                                                 nullptr, h1, nullptr, N);

    // ---- layer 1 ----
    wsplit<<<(128 * 128 + 255) / 256, 256, 0, stream>>>(W1, wth, wtl1, 128);
    gemm_mfma<<<gemm_blocks, 256, 0, stream>>>(h1, wth, wtl1, feat16, N, 128);
    eler_kernel<<<(N * 4 + 255) / 256, 256, 0, stream>>>(feat16, al1, ar1, el, er, N);
    edge_kernel<<<(E + 255) / 256, 256, 0, stream>>>(srcs, dsts, pos, el, er, exw,
                                                     e1_out, atten1_out, E);
    aggregate<1><<<agg_blocks, 256, 0, stream>>>(row_off, deg, csr_src, exw, feat16,
                                                 h1, out, heads, N);
}

// Round 3
// 452.942 us; speedup vs baseline: 1.4575x; 1.1532x over previous
//
#include <hip/hip_runtime.h>
#include <hip/hip_bf16.h>

// GAT 2-layer forward for MI355X (gfx950). Round 6: fusion round.
// - eler folded into gemm epilogue (el/er from f32 accs, shfl_xor reduce).
// - exw/pos intermediates deleted: aggregate computes exp(leaky(el[s]+er[d]))
//   inline (el 1.6MB L2-resident); edge pass slimmed to required outputs only.
// - fill_csr fused with layer-0 edge scoring (atten0).
// 11 launches (was 18).
//
// d_out (floats, return order):
//   [0, N*128)            temp = h2 flat
//   [N*128, N*128+4*N*32) heads h2[:,i]
//   [2*N*128, +E*4)       e1
//   [+E]                  atten0
//   [+E]                  atten1
//
// Workspace: feat16(N*128 f16) | h1(N*128 f32) | el(N*4) | er(N*4) |
//            wth/wtl (f16 split weights) | ints: deg(N) row_off(N) cursor(N)
//            csr_src(E) bsums(256)

typedef _Float16 f16;
typedef _Float16 f16x8 __attribute__((ext_vector_type(8)));
typedef float f32x4 __attribute__((ext_vector_type(4)));

// ---------------- W split: W[K][128] f32 -> Wth/Wtl [128][K] fp16 ------------
__global__ void wsplit(const float* __restrict__ W, f16* __restrict__ Wth,
                       f16* __restrict__ Wtl, int K) {
    int i = blockIdx.x * blockDim.x + threadIdx.x;
    if (i >= K * 128) return;
    int k = i >> 7, c = i & 127;
    float v = W[i];
    f16 h = (f16)v;
    f16 l = (f16)(v - (float)h);
    Wth[(size_t)c * K + k] = h;
    Wtl[(size_t)c * K + k] = l;
}

// ---------------- GEMM: Y16 = fp16(X @ W), fused el/er epilogue --------------
// fp16x3 split on mfma_f32_16x16x32_f16. Block 256 = 4 waves, tile 128x128.
// B cols staged permuted: staged ((p&7)<<4)|(p>>3) <=> phys p = lr*8 + cb,
// so lane lr owns 8 contiguous phys cols -> one f16x8 store per row, and its
// 8 accs are one quarter of head h = lr>>2 -> el/er via 16 fma + shfl_xor(1,2).
__global__ __launch_bounds__(256, 2) void gemm_mfma(
        const float* __restrict__ X, const f16* __restrict__ Wth,
        const f16* __restrict__ Wtl, f16* __restrict__ Y16,
        const float* __restrict__ al, const float* __restrict__ ar,
        float* __restrict__ el_out, float* __restrict__ er_out,
        int nrows, int K) {
    constexpr int STR = 40;  // fp16 stride: 80B rows -> 2-way bank alias (free)
    __shared__ f16 ash[128 * STR];
    __shared__ f16 asl[128 * STR];
    __shared__ f16 bsh[128 * STR];
    __shared__ f16 bsl[128 * STR];
    const int t    = threadIdx.x;
    const int wave = t >> 6;
    const int lane = t & 63;
    const int lr   = lane & 15;   // frag row (A) / col (B,D)
    const int kg   = lane >> 4;   // k-group 0..3
    const int row0 = blockIdx.x * 128;

    const int sr  = t >> 1;        // staging row (A) / physical col (B) 0..127
    const int sko = (t & 1) * 16;  // staging k offset 0/16
    const int ps  = ((sr & 7) << 4) | (sr >> 3);  // permuted staged B col
    int gr = row0 + sr; if (gr >= nrows) gr = nrows - 1;

    f32x4 acc[2][8];
    #pragma unroll
    for (int i = 0; i < 2; ++i)
        #pragma unroll
        for (int j = 0; j < 8; ++j) acc[i][j] = (f32x4){0.f, 0.f, 0.f, 0.f};

    for (int k0 = 0; k0 < K; k0 += 32) {
        // ---- stage A: X[row0..row0+127][k0..k0+31] f32 -> fp16 hi/lo ----
        {
            const float* xp = X + (size_t)gr * K + k0 + sko;
            float4 v0 = *(const float4*)(xp + 0);
            float4 v1 = *(const float4*)(xp + 4);
            float4 v2 = *(const float4*)(xp + 8);
            float4 v3 = *(const float4*)(xp + 12);
            float vv[16] = {v0.x, v0.y, v0.z, v0.w, v1.x, v1.y, v1.z, v1.w,
                            v2.x, v2.y, v2.z, v2.w, v3.x, v3.y, v3.z, v3.w};
            f16x8 H0, H1, L0, L1;
            #pragma unroll
            for (int i = 0; i < 8; ++i) {
                f16 h0 = (f16)vv[i];
                H0[i] = h0;
                L0[i] = (f16)(vv[i] - (float)h0);
                f16 h1 = (f16)vv[i + 8];
                H1[i] = h1;
                L1[i] = (f16)(vv[i + 8] - (float)h1);
            }
            *(f16x8*)&ash[sr * STR + sko]     = H0;
            *(f16x8*)&ash[sr * STR + sko + 8] = H1;
            *(f16x8*)&asl[sr * STR + sko]     = L0;
            *(f16x8*)&asl[sr * STR + sko + 8] = L1;
        }
        // ---- stage B (permuted): Wth/Wtl[physcol sr][k0..k0+31] fp16 ----
        {
            const f16* bph = Wth + (size_t)sr * K + k0 + sko;
            const f16* bpl = Wtl + (size_t)sr * K + k0 + sko;
            f16x8 b0 = *(const f16x8*)(bph);
            f16x8 b1 = *(const f16x8*)(bph + 8);
            f16x8 b2 = *(const f16x8*)(bpl);
            f16x8 b3 = *(const f16x8*)(bpl + 8);
            *(f16x8*)&bsh[ps * STR + sko]     = b0;
            *(f16x8*)&bsh[ps * STR + sko + 8] = b1;
            *(f16x8*)&bsl[ps * STR + sko]     = b2;
            *(f16x8*)&bsl[ps * STR + sko + 8] = b3;
        }
        __syncthreads();

        // ---- fragments ----
        const int arow = wave * 32 + lr;
        f16x8 ah0 = *(const f16x8*)&ash[arow * STR + kg * 8];
        f16x8 ah1 = *(const f16x8*)&ash[(arow + 16) * STR + kg * 8];
        f16x8 al0 = *(const f16x8*)&asl[arow * STR + kg * 8];
        f16x8 al1 = *(const f16x8*)&asl[(arow + 16) * STR + kg * 8];
        f16x8 bh[8];
        #pragma unroll
        for (int cb = 0; cb < 8; ++cb)
            bh[cb] = *(const f16x8*)&bsh[(cb * 16 + lr) * STR + kg * 8];

        // pass 1: Xh @ Wh
        #pragma unroll
        for (int cb = 0; cb < 8; ++cb) {
            acc[0][cb] = __builtin_amdgcn_mfma_f32_16x16x32_f16(ah0, bh[cb], acc[0][cb], 0, 0, 0);
            acc[1][cb] = __builtin_amdgcn_mfma_f32_16x16x32_f16(ah1, bh[cb], acc[1][cb], 0, 0, 0);
        }
        // pass 2: Xl @ Wh
        #pragma unroll
        for (int cb = 0; cb < 8; ++cb) {
            acc[0][cb] = __builtin_amdgcn_mfma_f32_16x16x32_f16(al0, bh[cb], acc[0][cb], 0, 0, 0);
            acc[1][cb] = __builtin_amdgcn_mfma_f32_16x16x32_f16(al1, bh[cb], acc[1][cb], 0, 0, 0);
        }
        // pass 3: Xh @ Wl (Wl streamed to keep VGPR down)
        #pragma unroll
        for (int cb = 0; cb < 8; ++cb) {
            f16x8 bl = *(const f16x8*)&bsl[(cb * 16 + lr) * STR + kg * 8];
            acc[0][cb] = __builtin_amdgcn_mfma_f32_16x16x32_f16(ah0, bl, acc[0][cb], 0, 0, 0);
            acc[1][cb] = __builtin_amdgcn_mfma_f32_16x16x32_f16(ah1, bl, acc[1][cb], 0, 0, 0);
        }
        __syncthreads();
    }

    // ---- epilogue: store f16 row chunks + fused el/er ----
    // lane owns phys cols lr*8..lr*8+7 = quarter (lr&3) of head h = lr>>2.
    const int hh = lr >> 2;
    const int co = (lr & 3) * 8;
    float alv[8], arv[8];
    #pragma unroll
    for (int j = 0; j < 8; ++j) {
        alv[j] = al[hh * 32 + co + j];
        arv[j] = ar[hh * 32 + co + j];
    }
    #pragma unroll
    for (int rb = 0; rb < 2; ++rb) {
        int rbase = row0 + wave * 32 + rb * 16 + kg * 4;
        #pragma unroll
        for (int r = 0; r < 4; ++r) {
            int grow = rbase + r;
            f16x8 hv;
            float sl_ = 0.0f, sr_ = 0.0f;
            #pragma unroll
            for (int cb = 0; cb < 8; ++cb) {
                float v = acc[rb][cb][r];
                hv[cb] = (f16)v;
                sl_ += v * alv[cb];
                sr_ += v * arv[cb];
            }
            // combine the 4 quarter-lanes of this head (lane bits 0,1)
            sl_ += __shfl_xor(sl_, 1); sl_ += __shfl_xor(sl_, 2);
            sr_ += __shfl_xor(sr_, 1); sr_ += __shfl_xor(sr_, 2);
            if (grow < nrows) {
                *(f16x8*)(Y16 + (size_t)grow * 128 + lr * 8) = hv;
                if ((lane & 3) == 0) {
                    el_out[4 * (size_t)grow + hh] = sl_;
                    er_out[4 * (size_t)grow + hh] = sr_;
                }
            }
        }
    }
}

// ---------------- CSR build ----------------
__global__ void count_deg(const int* __restrict__ dsts, int* __restrict__ deg, int E) {
    int e = blockIdx.x * blockDim.x + threadIdx.x;
    if (e < E) atomicAdd(&deg[dsts[e]], 1);
}

__global__ __launch_bounds__(256) void scan_block(const int* __restrict__ deg,
                                                  int* __restrict__ excl,
                                                  int* __restrict__ bsums, int n) {
    __shared__ int wsums[4];
    int t = threadIdx.x;
    int base = blockIdx.x * 1024;
    int idx = base + t * 4;
    int v[4];
    #pragma unroll
    for (int i = 0; i < 4; ++i) v[i] = (idx + i < n) ? deg[idx + i] : 0;
    int tsum = v[0] + v[1] + v[2] + v[3];
    int lane = t & 63, wid = t >> 6;
    int incl = tsum;
    #pragma unroll
    for (int off = 1; off < 64; off <<= 1) {
        int u = __shfl_up(incl, off, 64);
        if (lane >= off) incl += u;
    }
    if (lane == 63) wsums[wid] = incl;
    __syncthreads();
    if (t == 0) {
        int s = 0;
        #pragma unroll
        for (int w = 0; w < 4; ++w) { int x = wsums[w]; wsums[w] = s; s += x; }
    }
    __syncthreads();
    int ex = incl - tsum + wsums[wid];
    int run = ex;
    #pragma unroll
    for (int i = 0; i < 4; ++i) { if (idx + i < n) excl[idx + i] = run; run += v[i]; }
    if (t == 255) bsums[blockIdx.x] = ex + tsum;
}

__global__ __launch_bounds__(256) void scan_sums(int* __restrict__ bs, int nb) {
    __shared__ int wsums[4];
    int t = threadIdx.x;
    int v = (t < nb) ? bs[t] : 0;
    int lane = t & 63, wid = t >> 6;
    int incl = v;
    #pragma unroll
    for (int off = 1; off < 64; off <<= 1) {
        int u = __shfl_up(incl, off, 64);
        if (lane >= off) incl += u;
    }
    if (lane == 63) wsums[wid] = incl;
    __syncthreads();
    if (t == 0) {
        int s = 0;
        #pragma unroll
        for (int w = 0; w < 4; ++w) { int x = wsums[w]; wsums[w] = s; s += x; }
    }
    __syncthreads();
    if (t < nb) bs[t] = incl - v + wsums[wid];
}

__global__ void scan_finalize(int* __restrict__ row_off, const int* __restrict__ bsums,
                              int* __restrict__ cursor, int n) {
    int i = blockIdx.x * blockDim.x + threadIdx.x;
    if (i < n) {
        int v = row_off[i] + bsums[i >> 10];
        row_off[i] = v;
        cursor[i]  = v;
    }
}

// ---------------- fused: CSR fill + layer-0 edge scores (atten0) ------------
__global__ void fill_csr_edge0(const int* __restrict__ srcs, const int* __restrict__ dsts,
                               int* __restrict__ cursor, int* __restrict__ csr_src,
                               const float* __restrict__ el, const float* __restrict__ er,
                               float* __restrict__ atten0, int E) {
    int e = blockIdx.x * blockDim.x + threadIdx.x;
    if (e >= E) return;
    int s = srcs[e], d = dsts[e];
    int p = atomicAdd(&cursor[d], 1);
    csr_src[p] = s;
    float4 elv = *(const float4*)(el + 4 * (size_t)s);
    float4 erv = *(const float4*)(er + 4 * (size_t)d);
    float v0 = elv.x + erv.x, v1 = elv.y + erv.y;
    float v2 = elv.z + erv.z, v3 = elv.w + erv.w;
    v0 = v0 > 0.0f ? v0 : 0.2f * v0;
    v1 = v1 > 0.0f ? v1 : 0.2f * v1;
    v2 = v2 > 0.0f ? v2 : 0.2f * v2;
    v3 = v3 > 0.0f ? v3 : 0.2f * v3;
    atten0[e] = (v0 + v1 + v2 + v3) * 0.25f;
}

// ---------------- layer-1 edge pass: e1 + atten1 only -----------------------
__global__ void edge1_kernel(const int* __restrict__ srcs, const int* __restrict__ dsts,
                             const float* __restrict__ el, const float* __restrict__ er,
                             float* __restrict__ e1_out, float* __restrict__ atten1,
                             int E) {
    int e = blockIdx.x * blockDim.x + threadIdx.x;
    if (e >= E) return;
    int s = srcs[e], d = dsts[e];
    float4 elv = *(const float4*)(el + 4 * (size_t)s);
    float4 erv = *(const float4*)(er + 4 * (size_t)d);
    float v0 = elv.x + erv.x, v1 = elv.y + erv.y;
    float v2 = elv.z + erv.z, v3 = elv.w + erv.w;
    v0 = v0 > 0.0f ? v0 : 0.2f * v0;
    v1 = v1 > 0.0f ? v1 : 0.2f * v1;
    v2 = v2 > 0.0f ? v2 : 0.2f * v2;
    v3 = v3 > 0.0f ? v3 : 0.2f * v3;
    *(float4*)(e1_out + 4 * (size_t)e) = make_float4(v0, v1, v2, v3);
    atten1[e] = (v0 + v1 + v2 + v3) * 0.25f;
}

// ---------------- gather aggregation: one wave per dst node -----------------
// Lane = (quarter q, col-slot sc). Quarter q handles edges i+q; each lane loads
// a contiguous f16x8 (16B) of feat16[src]. Weight w computed INLINE:
// w = exp(leaky(el[4s+h] + er[4d+h])) -- el is L2-resident, no exw stream.
template <int LAYER>
__global__ __launch_bounds__(256) void aggregate(const int* __restrict__ row_off,
                                                 const int* __restrict__ deg,
                                                 const int* __restrict__ csr_src,
                                                 const float* __restrict__ el,
                                                 const float* __restrict__ er,
                                                 const f16* __restrict__ feat16,
                                                 const float* __restrict__ resid,
                                                 float* __restrict__ out0,
                                                 float* __restrict__ heads,
                                                 int N) {
    int wave = (blockIdx.x * 256 + threadIdx.x) >> 6;
    if (wave >= N) return;
    int lane = threadIdx.x & 63;
    int q  = lane >> 4;          // edge phase 0..3
    int sc = lane & 15;          // col slot: cols sc*8 .. sc*8+7
    int h  = sc >> 2;            // head of these cols
    int start = row_off[wave];
    int dc    = deg[wave];
    float er_h = er[4 * (size_t)wave + h];

    float acc[8];
    #pragma unroll
    for (int j = 0; j < 8; ++j) acc[j] = 0.0f;
    float dh = 0.0f;

    for (int cs = 0; cs < dc; cs += 64) {
        int act = dc - cs; if (act > 64) act = 64;
        int sl = (lane < act) ? csr_src[start + cs + lane] : 0;
        int i = 0;
        for (; i + 8 <= act; i += 8) {
            int s0 = __shfl(sl, i + q);
            int s1 = __shfl(sl, i + 4 + q);
            float x0 = el[4 * (size_t)s0 + h] + er_h;
            float x1 = el[4 * (size_t)s1 + h] + er_h;
            x0 = x0 > 0.0f ? x0 : 0.2f * x0;
            x1 = x1 > 0.0f ? x1 : 0.2f * x1;
            float w0 = __expf(x0);
            float w1 = __expf(x1);
            f16x8 f0 = *(const f16x8*)(feat16 + 128 * (size_t)s0 + sc * 8);
            f16x8 f1 = *(const f16x8*)(feat16 + 128 * (size_t)s1 + sc * 8);
            #pragma unroll
            for (int j = 0; j < 8; ++j) acc[j] += w0 * (float)f0[j];
            #pragma unroll
            for (int j = 0; j < 8; ++j) acc[j] += w1 * (float)f1[j];
            dh += w0 + w1;
        }
        for (; i < act; i += 4) {
            int e = i + q;
            bool on = e < act;
            int s = __shfl(sl, on ? e : 0);
            float x = el[4 * (size_t)s + h] + er_h;
            x = x > 0.0f ? x : 0.2f * x;
            float w = on ? __expf(x) : 0.0f;
            f16x8 fv = *(const f16x8*)(feat16 + 128 * (size_t)s + sc * 8);
            #pragma unroll
            for (int j = 0; j < 8; ++j) acc[j] += w * (float)fv[j];
            dh += w;
        }
    }

    // combine the 4 quarter-partials (xor16/32 flip q bits; sc preserved)
    #pragma unroll
    for (int j = 0; j < 8; ++j) {
        acc[j] += __shfl_xor(acc[j], 16);
        acc[j] += __shfl_xor(acc[j], 32);
    }
    dh += __shfl_xor(dh, 16);
    dh += __shfl_xor(dh, 32);

    float inv = (dc > 0) ? 1.0f / dh : 0.0f;
    // each lane writes cols c0 = sc*8 + q*2, +1 (static-index select)
    float ax = (q == 0) ? acc[0] : (q == 1) ? acc[2] : (q == 2) ? acc[4] : acc[6];
    float ay = (q == 0) ? acc[1] : (q == 1) ? acc[3] : (q == 2) ? acc[5] : acc[7];
    ax *= inv; ay *= inv;
    int c0 = sc * 8 + q * 2;
    size_t o = 128 * (size_t)wave + c0;
    if (LAYER == 1) {
        float2 rv = *(const float2*)(resid + o);
        ax += rv.x; ay += rv.y;
    }
    ax = ax > 0.0f ? ax : __expf(ax) - 1.0f;
    ay = ay > 0.0f ? ay : __expf(ay) - 1.0f;
    *(float2*)(out0 + o) = make_float2(ax, ay);
    if (LAYER == 1) {
        *(float2*)(heads + (size_t)h * N * 32 + (size_t)wave * 32 + (c0 & 31)) =
            make_float2(ax, ay);
    }
}

extern "C" void kernel_launch(void* const* d_in, const int* in_sizes, int n_in,
                              void* d_out, int out_size, void* d_ws, size_t ws_size,
                              hipStream_t stream) {
    const float* x   = (const float*)d_in[0];
    const int*   ei  = (const int*)d_in[1];
    const float* W0  = (const float*)d_in[2];
    const float* al0 = (const float*)d_in[3];
    const float* ar0 = (const float*)d_in[4];
    const float* W1  = (const float*)d_in[5];
    const float* al1 = (const float*)d_in[6];
    const float* ar1 = (const float*)d_in[7];

    const int N = in_sizes[0] / 256;     // 100000
    const int E = in_sizes[1] / 2;       // 800000
    const size_t NF = (size_t)N * 128;

    const int* srcs = ei;
    const int* dsts = ei + E;

    float* out = (float*)d_out;
    float* ws  = (float*)d_ws;
    f16*   feat16 = (f16*)ws;                            // N*128 f16 (NF-float slot)
    float* h1   = ws + NF;                               // N*128 f32
    float* el   = ws + 2 * NF;                           // N*4
    float* er   = el + (size_t)N * 4;                    // N*4
    f16*   wth  = (f16*)(er + (size_t)N * 4);            // 128*256 f16
    f16*   wtl0 = wth + (size_t)128 * 256;               // layer0 lo
    f16*   wtl1 = wth + (size_t)128 * 128;               // layer1 lo (after K=128 hi)
    int*   ints    = (int*)(wth + (size_t)2 * 128 * 256);
    int*   deg     = ints;                               // N
    int*   row_off = deg + N;                            // N
    int*   cursor  = row_off + N;                        // N
    int*   csr_src = cursor + N;                         // E
    int*   bsums   = csr_src + E;                        // <=256

    float* heads      = out + NF;
    float* e1_out     = out + 2 * NF;
    float* atten0_out = e1_out + (size_t)E * 4;
    float* atten1_out = atten0_out + E;

    // ---- CSR degree + offsets (independent of layer-0 GEMM) ----
    hipMemsetAsync(deg, 0, (size_t)N * sizeof(int), stream);
    count_deg<<<(E + 255) / 256, 256, 0, stream>>>(dsts, deg, E);
    int nb = (N + 1023) / 1024;
    scan_block<<<nb, 256, 0, stream>>>(deg, row_off, bsums, N);
    scan_sums<<<1, 256, 0, stream>>>(bsums, nb);
    scan_finalize<<<(N + 255) / 256, 256, 0, stream>>>(row_off, bsums, cursor, N);

    const int gemm_blocks = (N + 127) / 128;
    const int agg_blocks  = (N + 3) / 4;

    // ---- layer 0 ----
    wsplit<<<(256 * 128 + 255) / 256, 256, 0, stream>>>(W0, wth, wtl0, 256);
    gemm_mfma<<<gemm_blocks, 256, 0, stream>>>(x, wth, wtl0, feat16, al0, ar0,
                                               el, er, N, 256);
    fill_csr_edge0<<<(E + 255) / 256, 256, 0, stream>>>(srcs, dsts, cursor, csr_src,
                                                        el, er, atten0_out, E);
    aggregate<0><<<agg_blocks, 256, 0, stream>>>(row_off, deg, csr_src, el, er,
                                                 feat16, nullptr, h1, nullptr, N);

    // ---- layer 1 ----
    wsplit<<<(128 * 128 + 255) / 256, 256, 0, stream>>>(W1, wth, wtl1, 128);
    gemm_mfma<<<gemm_blocks, 256, 0, stream>>>(h1, wth, wtl1, feat16, al1, ar1,
                                               el, er, N, 128);
    edge1_kernel<<<(E + 255) / 256, 256, 0, stream>>>(srcs, dsts, el, er,
                                                      e1_out, atten1_out, E);
    aggregate<1><<<agg_blocks, 256, 0, stream>>>(row_off, deg, csr_src, el, er,
                                                 feat16, h1, out, heads, N);
}

// Round 4
// 443.466 us; speedup vs baseline: 1.4886x; 1.0214x over previous
//
#include <hip/hip_runtime.h>
#include <hip/hip_bf16.h>

// GAT 2-layer forward for MI355X (gfx950). Round 7: h1 stored fp16-only.
// - aggregate<0> writes h1 as f16 (write traffic halved).
// - gemm layer-1 takes fp16 A directly: lo-part of A is exactly 0, so the
//   fp16x3 split collapses to 2 MFMA passes (Ah@Wh + Ah@Wl) with no cvt VALU.
// - aggregate<1> reads the residual as f16.
// - single wsplit2 launch splits W0 and W1 up front (separate buffers).
// 10 launches + 1 memset.
//
// d_out (floats, return order):
//   [0, N*128)            temp = h2 flat
//   [N*128, N*128+4*N*32) heads h2[:,i]
//   [2*N*128, +E*4)       e1
//   [+E]                  atten0
//   [+E]                  atten1
//
// Workspace: feat16(N*128 f16) | h1_16(N*128 f16) | el(N*4) | er(N*4) |
//            wth0/wtl0/wth1/wtl1 (f16 split weights) |
//            ints: deg(N) row_off(N) cursor(N) csr_src(E) bsums(256)

typedef _Float16 f16;
typedef _Float16 f16x2 __attribute__((ext_vector_type(2)));
typedef _Float16 f16x8 __attribute__((ext_vector_type(8)));
typedef float f32x4 __attribute__((ext_vector_type(4)));

// ------------- W split (both layers): W[K][128] f32 -> [128][K] f16 hi/lo ----
__global__ void wsplit2(const float* __restrict__ W0, const float* __restrict__ W1,
                        f16* __restrict__ Wth0, f16* __restrict__ Wtl0,
                        f16* __restrict__ Wth1, f16* __restrict__ Wtl1) {
    int i = blockIdx.x * blockDim.x + threadIdx.x;
    if (i < 256 * 128) {
        int k = i >> 7, c = i & 127;
        float v = W0[i];
        f16 h = (f16)v;
        Wth0[(size_t)c * 256 + k] = h;
        Wtl0[(size_t)c * 256 + k] = (f16)(v - (float)h);
    } else if (i < 256 * 128 + 128 * 128) {
        int j = i - 256 * 128;
        int k = j >> 7, c = j & 127;
        float v = W1[j];
        f16 h = (f16)v;
        Wth1[(size_t)c * 128 + k] = h;
        Wtl1[(size_t)c * 128 + k] = (f16)(v - (float)h);
    }
}

// ---------------- GEMM: Y16 = fp16(X @ W), fused el/er epilogue --------------
// AFP16=0: X is f32, split into fp16 hi/lo in staging -> 3 MFMA passes.
// AFP16=1: X is already f16 -> lo is exactly 0 -> 2 MFMA passes, no cvt.
// Block 256 = 4 waves, tile 128x128. B cols staged permuted:
// staged ((p&7)<<4)|(p>>3) <=> phys p = lr*8 + cb, so lane lr owns 8
// contiguous phys cols -> one f16x8 store per row; its 8 accs are one quarter
// of head h = lr>>2 -> el/er via 16 fma + shfl_xor(1,2).
template <int AFP16>
__global__ __launch_bounds__(256, 2) void gemm_mfma(
        const void* __restrict__ Xv, const f16* __restrict__ Wth,
        const f16* __restrict__ Wtl, f16* __restrict__ Y16,
        const float* __restrict__ al, const float* __restrict__ ar,
        float* __restrict__ el_out, float* __restrict__ er_out,
        int nrows, int K) {
    constexpr int STR = 40;  // fp16 stride: 80B rows -> 2-way bank alias (free)
    __shared__ f16 ash[128 * STR];
    __shared__ f16 asl[AFP16 ? 2 : 128 * STR];   // unused when AFP16
    __shared__ f16 bsh[128 * STR];
    __shared__ f16 bsl[128 * STR];
    const int t    = threadIdx.x;
    const int wave = t >> 6;
    const int lane = t & 63;
    const int lr   = lane & 15;   // frag row (A) / col (B,D)
    const int kg   = lane >> 4;   // k-group 0..3
    const int row0 = blockIdx.x * 128;

    const int sr  = t >> 1;        // staging row (A) / physical col (B) 0..127
    const int sko = (t & 1) * 16;  // staging k offset 0/16
    const int ps  = ((sr & 7) << 4) | (sr >> 3);  // permuted staged B col
    int gr = row0 + sr; if (gr >= nrows) gr = nrows - 1;

    f32x4 acc[2][8];
    #pragma unroll
    for (int i = 0; i < 2; ++i)
        #pragma unroll
        for (int j = 0; j < 8; ++j) acc[i][j] = (f32x4){0.f, 0.f, 0.f, 0.f};

    for (int k0 = 0; k0 < K; k0 += 32) {
        // ---- stage A ----
        if constexpr (!AFP16) {
            const float* xp = (const float*)Xv + (size_t)gr * K + k0 + sko;
            float4 v0 = *(const float4*)(xp + 0);
            float4 v1 = *(const float4*)(xp + 4);
            float4 v2 = *(const float4*)(xp + 8);
            float4 v3 = *(const float4*)(xp + 12);
            float vv[16] = {v0.x, v0.y, v0.z, v0.w, v1.x, v1.y, v1.z, v1.w,
                            v2.x, v2.y, v2.z, v2.w, v3.x, v3.y, v3.z, v3.w};
            f16x8 H0, H1, L0, L1;
            #pragma unroll
            for (int i = 0; i < 8; ++i) {
                f16 h0 = (f16)vv[i];
                H0[i] = h0;
                L0[i] = (f16)(vv[i] - (float)h0);
                f16 h1 = (f16)vv[i + 8];
                H1[i] = h1;
                L1[i] = (f16)(vv[i + 8] - (float)h1);
            }
            *(f16x8*)&ash[sr * STR + sko]     = H0;
            *(f16x8*)&ash[sr * STR + sko + 8] = H1;
            *(f16x8*)&asl[sr * STR + sko]     = L0;
            *(f16x8*)&asl[sr * STR + sko + 8] = L1;
        } else {
            const f16* xp = (const f16*)Xv + (size_t)gr * K + k0 + sko;
            f16x8 a0 = *(const f16x8*)(xp);
            f16x8 a1 = *(const f16x8*)(xp + 8);
            *(f16x8*)&ash[sr * STR + sko]     = a0;
            *(f16x8*)&ash[sr * STR + sko + 8] = a1;
        }
        // ---- stage B (permuted): Wth/Wtl[physcol sr][k0..k0+31] fp16 ----
        {
            const f16* bph = Wth + (size_t)sr * K + k0 + sko;
            const f16* bpl = Wtl + (size_t)sr * K + k0 + sko;
            f16x8 b0 = *(const f16x8*)(bph);
            f16x8 b1 = *(const f16x8*)(bph + 8);
            f16x8 b2 = *(const f16x8*)(bpl);
            f16x8 b3 = *(const f16x8*)(bpl + 8);
            *(f16x8*)&bsh[ps * STR + sko]     = b0;
            *(f16x8*)&bsh[ps * STR + sko + 8] = b1;
            *(f16x8*)&bsl[ps * STR + sko]     = b2;
            *(f16x8*)&bsl[ps * STR + sko + 8] = b3;
        }
        __syncthreads();

        // ---- fragments ----
        const int arow = wave * 32 + lr;
        f16x8 ah0 = *(const f16x8*)&ash[arow * STR + kg * 8];
        f16x8 ah1 = *(const f16x8*)&ash[(arow + 16) * STR + kg * 8];
        f16x8 bh[8];
        #pragma unroll
        for (int cb = 0; cb < 8; ++cb)
            bh[cb] = *(const f16x8*)&bsh[(cb * 16 + lr) * STR + kg * 8];

        // pass 1: Ah @ Wh
        #pragma unroll
        for (int cb = 0; cb < 8; ++cb) {
            acc[0][cb] = __builtin_amdgcn_mfma_f32_16x16x32_f16(ah0, bh[cb], acc[0][cb], 0, 0, 0);
            acc[1][cb] = __builtin_amdgcn_mfma_f32_16x16x32_f16(ah1, bh[cb], acc[1][cb], 0, 0, 0);
        }
        // pass 2: Al @ Wh (only when A was f32)
        if constexpr (!AFP16) {
            f16x8 al0_ = *(const f16x8*)&asl[arow * STR + kg * 8];
            f16x8 al1_ = *(const f16x8*)&asl[(arow + 16) * STR + kg * 8];
            #pragma unroll
            for (int cb = 0; cb < 8; ++cb) {
                acc[0][cb] = __builtin_amdgcn_mfma_f32_16x16x32_f16(al0_, bh[cb], acc[0][cb], 0, 0, 0);
                acc[1][cb] = __builtin_amdgcn_mfma_f32_16x16x32_f16(al1_, bh[cb], acc[1][cb], 0, 0, 0);
            }
        }
        // pass 3: Ah @ Wl (Wl streamed to keep VGPR down)
        #pragma unroll
        for (int cb = 0; cb < 8; ++cb) {
            f16x8 bl = *(const f16x8*)&bsl[(cb * 16 + lr) * STR + kg * 8];
            acc[0][cb] = __builtin_amdgcn_mfma_f32_16x16x32_f16(ah0, bl, acc[0][cb], 0, 0, 0);
            acc[1][cb] = __builtin_amdgcn_mfma_f32_16x16x32_f16(ah1, bl, acc[1][cb], 0, 0, 0);
        }
        __syncthreads();
    }

    // ---- epilogue: store f16 row chunks + fused el/er ----
    // lane owns phys cols lr*8..lr*8+7 = quarter (lr&3) of head h = lr>>2.
    const int hh = lr >> 2;
    const int co = (lr & 3) * 8;
    float alv[8], arv[8];
    #pragma unroll
    for (int j = 0; j < 8; ++j) {
        alv[j] = al[hh * 32 + co + j];
        arv[j] = ar[hh * 32 + co + j];
    }
    #pragma unroll
    for (int rb = 0; rb < 2; ++rb) {
        int rbase = row0 + wave * 32 + rb * 16 + kg * 4;
        #pragma unroll
        for (int r = 0; r < 4; ++r) {
            int grow = rbase + r;
            f16x8 hv;
            float sl_ = 0.0f, sr_ = 0.0f;
            #pragma unroll
            for (int cb = 0; cb < 8; ++cb) {
                float v = acc[rb][cb][r];
                hv[cb] = (f16)v;
                sl_ += v * alv[cb];
                sr_ += v * arv[cb];
            }
            // combine the 4 quarter-lanes of this head (lane bits 0,1)
            sl_ += __shfl_xor(sl_, 1); sl_ += __shfl_xor(sl_, 2);
            sr_ += __shfl_xor(sr_, 1); sr_ += __shfl_xor(sr_, 2);
            if (grow < nrows) {
                *(f16x8*)(Y16 + (size_t)grow * 128 + lr * 8) = hv;
                if ((lane & 3) == 0) {
                    el_out[4 * (size_t)grow + hh] = sl_;
                    er_out[4 * (size_t)grow + hh] = sr_;
                }
            }
        }
    }
}

// ---------------- CSR build ----------------
__global__ void count_deg(const int* __restrict__ dsts, int* __restrict__ deg, int E) {
    int e = blockIdx.x * blockDim.x + threadIdx.x;
    if (e < E) atomicAdd(&deg[dsts[e]], 1);
}

__global__ __launch_bounds__(256) void scan_block(const int* __restrict__ deg,
                                                  int* __restrict__ excl,
                                                  int* __restrict__ bsums, int n) {
    __shared__ int wsums[4];
    int t = threadIdx.x;
    int base = blockIdx.x * 1024;
    int idx = base + t * 4;
    int v[4];
    #pragma unroll
    for (int i = 0; i < 4; ++i) v[i] = (idx + i < n) ? deg[idx + i] : 0;
    int tsum = v[0] + v[1] + v[2] + v[3];
    int lane = t & 63, wid = t >> 6;
    int incl = tsum;
    #pragma unroll
    for (int off = 1; off < 64; off <<= 1) {
        int u = __shfl_up(incl, off, 64);
        if (lane >= off) incl += u;
    }
    if (lane == 63) wsums[wid] = incl;
    __syncthreads();
    if (t == 0) {
        int s = 0;
        #pragma unroll
        for (int w = 0; w < 4; ++w) { int x = wsums[w]; wsums[w] = s; s += x; }
    }
    __syncthreads();
    int ex = incl - tsum + wsums[wid];
    int run = ex;
    #pragma unroll
    for (int i = 0; i < 4; ++i) { if (idx + i < n) excl[idx + i] = run; run += v[i]; }
    if (t == 255) bsums[blockIdx.x] = ex + tsum;
}

__global__ __launch_bounds__(256) void scan_sums(int* __restrict__ bs, int nb) {
    __shared__ int wsums[4];
    int t = threadIdx.x;
    int v = (t < nb) ? bs[t] : 0;
    int lane = t & 63, wid = t >> 6;
    int incl = v;
    #pragma unroll
    for (int off = 1; off < 64; off <<= 1) {
        int u = __shfl_up(incl, off, 64);
        if (lane >= off) incl += u;
    }
    if (lane == 63) wsums[wid] = incl;
    __syncthreads();
    if (t == 0) {
        int s = 0;
        #pragma unroll
        for (int w = 0; w < 4; ++w) { int x = wsums[w]; wsums[w] = s; s += x; }
    }
    __syncthreads();
    if (t < nb) bs[t] = incl - v + wsums[wid];
}

__global__ void scan_finalize(int* __restrict__ row_off, const int* __restrict__ bsums,
                              int* __restrict__ cursor, int n) {
    int i = blockIdx.x * blockDim.x + threadIdx.x;
    if (i < n) {
        int v = row_off[i] + bsums[i >> 10];
        row_off[i] = v;
        cursor[i]  = v;
    }
}

// ---------------- fused: CSR fill + layer-0 edge scores (atten0) ------------
__global__ void fill_csr_edge0(const int* __restrict__ srcs, const int* __restrict__ dsts,
                               int* __restrict__ cursor, int* __restrict__ csr_src,
                               const float* __restrict__ el, const float* __restrict__ er,
                               float* __restrict__ atten0, int E) {
    int e = blockIdx.x * blockDim.x + threadIdx.x;
    if (e >= E) return;
    int s = srcs[e], d = dsts[e];
    int p = atomicAdd(&cursor[d], 1);
    csr_src[p] = s;
    float4 elv = *(const float4*)(el + 4 * (size_t)s);
    float4 erv = *(const float4*)(er + 4 * (size_t)d);
    float v0 = elv.x + erv.x, v1 = elv.y + erv.y;
    float v2 = elv.z + erv.z, v3 = elv.w + erv.w;
    v0 = v0 > 0.0f ? v0 : 0.2f * v0;
    v1 = v1 > 0.0f ? v1 : 0.2f * v1;
    v2 = v2 > 0.0f ? v2 : 0.2f * v2;
    v3 = v3 > 0.0f ? v3 : 0.2f * v3;
    atten0[e] = (v0 + v1 + v2 + v3) * 0.25f;
}

// ---------------- layer-1 edge pass: e1 + atten1 only -----------------------
__global__ void edge1_kernel(const int* __restrict__ srcs, const int* __restrict__ dsts,
                             const float* __restrict__ el, const float* __restrict__ er,
                             float* __restrict__ e1_out, float* __restrict__ atten1,
                             int E) {
    int e = blockIdx.x * blockDim.x + threadIdx.x;
    if (e >= E) return;
    int s = srcs[e], d = dsts[e];
    float4 elv = *(const float4*)(el + 4 * (size_t)s);
    float4 erv = *(const float4*)(er + 4 * (size_t)d);
    float v0 = elv.x + erv.x, v1 = elv.y + erv.y;
    float v2 = elv.z + erv.z, v3 = elv.w + erv.w;
    v0 = v0 > 0.0f ? v0 : 0.2f * v0;
    v1 = v1 > 0.0f ? v1 : 0.2f * v1;
    v2 = v2 > 0.0f ? v2 : 0.2f * v2;
    v3 = v3 > 0.0f ? v3 : 0.2f * v3;
    *(float4*)(e1_out + 4 * (size_t)e) = make_float4(v0, v1, v2, v3);
    atten1[e] = (v0 + v1 + v2 + v3) * 0.25f;
}

// ---------------- gather aggregation: one wave per dst node -----------------
// Lane = (quarter q, col-slot sc). Quarter q handles edges i+q; each lane loads
// a contiguous f16x8 (16B) of feat16[src]. Weight w computed INLINE:
// w = exp(leaky(el[4s+h] + er[4d+h])) -- el is L2-resident, no exw stream.
// LAYER 0: writes h1 as f16. LAYER 1: reads f16 residual, writes f32 out+heads.
template <int LAYER>
__global__ __launch_bounds__(256) void aggregate(const int* __restrict__ row_off,
                                                 const int* __restrict__ deg,
                                                 const int* __restrict__ csr_src,
                                                 const float* __restrict__ el,
                                                 const float* __restrict__ er,
                                                 const f16* __restrict__ feat16,
                                                 const f16* __restrict__ resid16,
                                                 f16* __restrict__ out16,
                                                 float* __restrict__ out32,
                                                 float* __restrict__ heads,
                                                 int N) {
    int wave = (blockIdx.x * 256 + threadIdx.x) >> 6;
    if (wave >= N) return;
    int lane = threadIdx.x & 63;
    int q  = lane >> 4;          // edge phase 0..3
    int sc = lane & 15;          // col slot: cols sc*8 .. sc*8+7
    int h  = sc >> 2;            // head of these cols
    int start = row_off[wave];
    int dc    = deg[wave];
    float er_h = er[4 * (size_t)wave + h];

    float acc[8];
    #pragma unroll
    for (int j = 0; j < 8; ++j) acc[j] = 0.0f;
    float dh = 0.0f;

    for (int cs = 0; cs < dc; cs += 64) {
        int act = dc - cs; if (act > 64) act = 64;
        int sl = (lane < act) ? csr_src[start + cs + lane] : 0;
        int i = 0;
        for (; i + 8 <= act; i += 8) {
            int s0 = __shfl(sl, i + q);
            int s1 = __shfl(sl, i + 4 + q);
            float x0 = el[4 * (size_t)s0 + h] + er_h;
            float x1 = el[4 * (size_t)s1 + h] + er_h;
            x0 = x0 > 0.0f ? x0 : 0.2f * x0;
            x1 = x1 > 0.0f ? x1 : 0.2f * x1;
            float w0 = __expf(x0);
            float w1 = __expf(x1);
            f16x8 f0 = *(const f16x8*)(feat16 + 128 * (size_t)s0 + sc * 8);
            f16x8 f1 = *(const f16x8*)(feat16 + 128 * (size_t)s1 + sc * 8);
            #pragma unroll
            for (int j = 0; j < 8; ++j) acc[j] += w0 * (float)f0[j];
            #pragma unroll
            for (int j = 0; j < 8; ++j) acc[j] += w1 * (float)f1[j];
            dh += w0 + w1;
        }
        for (; i < act; i += 4) {
            int e = i + q;
            bool on = e < act;
            int s = __shfl(sl, on ? e : 0);
            float x = el[4 * (size_t)s + h] + er_h;
            x = x > 0.0f ? x : 0.2f * x;
            float w = on ? __expf(x) : 0.0f;
            f16x8 fv = *(const f16x8*)(feat16 + 128 * (size_t)s + sc * 8);
            #pragma unroll
            for (int j = 0; j < 8; ++j) acc[j] += w * (float)fv[j];
            dh += w;
        }
    }

    // combine the 4 quarter-partials (xor16/32 flip q bits; sc preserved)
    #pragma unroll
    for (int j = 0; j < 8; ++j) {
        acc[j] += __shfl_xor(acc[j], 16);
        acc[j] += __shfl_xor(acc[j], 32);
    }
    dh += __shfl_xor(dh, 16);
    dh += __shfl_xor(dh, 32);

    float inv = (dc > 0) ? 1.0f / dh : 0.0f;
    // each lane writes cols c0 = sc*8 + q*2, +1 (static-index select)
    float ax = (q == 0) ? acc[0] : (q == 1) ? acc[2] : (q == 2) ? acc[4] : acc[6];
    float ay = (q == 0) ? acc[1] : (q == 1) ? acc[3] : (q == 2) ? acc[5] : acc[7];
    ax *= inv; ay *= inv;
    int c0 = sc * 8 + q * 2;
    size_t o = 128 * (size_t)wave + c0;
    if (LAYER == 1) {
        f16x2 rv = *(const f16x2*)(resid16 + o);
        ax += (float)rv[0]; ay += (float)rv[1];
    }
    ax = ax > 0.0f ? ax : __expf(ax) - 1.0f;
    ay = ay > 0.0f ? ay : __expf(ay) - 1.0f;
    if (LAYER == 0) {
        f16x2 hv; hv[0] = (f16)ax; hv[1] = (f16)ay;
        *(f16x2*)(out16 + o) = hv;
    } else {
        *(float2*)(out32 + o) = make_float2(ax, ay);
        *(float2*)(heads + (size_t)h * N * 32 + (size_t)wave * 32 + (c0 & 31)) =
            make_float2(ax, ay);
    }
}

extern "C" void kernel_launch(void* const* d_in, const int* in_sizes, int n_in,
                              void* d_out, int out_size, void* d_ws, size_t ws_size,
                              hipStream_t stream) {
    const float* x   = (const float*)d_in[0];
    const int*   ei  = (const int*)d_in[1];
    const float* W0  = (const float*)d_in[2];
    const float* al0 = (const float*)d_in[3];
    const float* ar0 = (const float*)d_in[4];
    const float* W1  = (const float*)d_in[5];
    const float* al1 = (const float*)d_in[6];
    const float* ar1 = (const float*)d_in[7];

    const int N = in_sizes[0] / 256;     // 100000
    const int E = in_sizes[1] / 2;       // 800000
    const size_t NF = (size_t)N * 128;

    const int* srcs = ei;
    const int* dsts = ei + E;

    float* out = (float*)d_out;
    f16*   f16ws  = (f16*)d_ws;
    f16*   feat16 = f16ws;                               // N*128 f16
    f16*   h1_16  = feat16 + NF;                         // N*128 f16
    float* el   = (float*)(h1_16 + NF);                  // N*4
    float* er   = el + (size_t)N * 4;                    // N*4
    f16*   wth0 = (f16*)(er + (size_t)N * 4);            // 128*256
    f16*   wtl0 = wth0 + (size_t)128 * 256;              // 128*256
    f16*   wth1 = wtl0 + (size_t)128 * 256;              // 128*128
    f16*   wtl1 = wth1 + (size_t)128 * 128;              // 128*128
    int*   ints    = (int*)(wtl1 + (size_t)128 * 128);
    int*   deg     = ints;                               // N
    int*   row_off = deg + N;                            // N
    int*   cursor  = row_off + N;                        // N
    int*   csr_src = cursor + N;                         // E
    int*   bsums   = csr_src + E;                        // <=256

    float* heads      = out + NF;
    float* e1_out     = out + 2 * NF;
    float* atten0_out = e1_out + (size_t)E * 4;
    float* atten1_out = atten0_out + E;

    // ---- weight split (both layers, one launch) ----
    const int wtot = 256 * 128 + 128 * 128;
    wsplit2<<<(wtot + 255) / 256, 256, 0, stream>>>(W0, W1, wth0, wtl0, wth1, wtl1);

    // ---- CSR degree + offsets (independent of layer-0 GEMM) ----
    hipMemsetAsync(deg, 0, (size_t)N * sizeof(int), stream);
    count_deg<<<(E + 255) / 256, 256, 0, stream>>>(dsts, deg, E);
    int nb = (N + 1023) / 1024;
    scan_block<<<nb, 256, 0, stream>>>(deg, row_off, bsums, N);
    scan_sums<<<1, 256, 0, stream>>>(bsums, nb);
    scan_finalize<<<(N + 255) / 256, 256, 0, stream>>>(row_off, bsums, cursor, N);

    const int gemm_blocks = (N + 127) / 128;
    const int agg_blocks  = (N + 3) / 4;

    // ---- layer 0 ----
    gemm_mfma<0><<<gemm_blocks, 256, 0, stream>>>(x, wth0, wtl0, feat16, al0, ar0,
                                                  el, er, N, 256);
    fill_csr_edge0<<<(E + 255) / 256, 256, 0, stream>>>(srcs, dsts, cursor, csr_src,
                                                        el, er, atten0_out, E);
    aggregate<0><<<agg_blocks, 256, 0, stream>>>(row_off, deg, csr_src, el, er,
                                                 feat16, nullptr, h1_16, nullptr,
                                                 nullptr, N);

    // ---- layer 1 ----
    gemm_mfma<1><<<gemm_blocks, 256, 0, stream>>>(h1_16, wth1, wtl1, feat16, al1, ar1,
                                                  el, er, N, 128);
    edge1_kernel<<<(E + 255) / 256, 256, 0, stream>>>(srcs, dsts, el, er,
                                                      e1_out, atten1_out, E);
    aggregate<1><<<agg_blocks, 256, 0, stream>>>(row_off, deg, csr_src, el, er,
                                                 feat16, h1_16, nullptr, out,
                                                 heads, N);
}

// Round 5
// 427.013 us; speedup vs baseline: 1.5460x; 1.0385x over previous
//
#include <hip/hip_runtime.h>
#include <hip/hip_bf16.h>

// GAT 2-layer forward for MI355X (gfx950). Round 8: async staging round.
// - gemm_mfma staged entirely via __builtin_amdgcn_global_load_lds (16B):
//   B/A-f16 linear [128][32] (64B rows, conflict-benign), source carries the
//   col permutation; A-f32 (layer 0) uses a 16B-granule XOR swizzle
//   (slot = g ^ (row&7), involution; pre-swizzled source + swizzled read),
//   hi/lo fp16 split moved to frag-read time. No ds_writes, no staging VALU.
// - prep = wsplit2 + count_deg fused; scan_sums+scan_finalize fused.
// - non-temporal stores for out/heads/e1/atten streams (protect feat16 L2).
// 9 launches + 1 memset.
//
// d_out (floats): temp[N*128] | heads[4][N*32] | e1[E*4] | atten0[E] | atten1[E]
// Workspace: feat16(N*128 f16) | h1_16(N*128 f16) | el(N*4) | er(N*4) |
//            wth0/wtl0/wth1/wtl1 | ints: deg(N) row_off(N) cursor(N)
//            csr_src(E) bsums(256)

typedef _Float16 f16;
typedef _Float16 f16x2 __attribute__((ext_vector_type(2)));
typedef _Float16 f16x8 __attribute__((ext_vector_type(8)));
typedef float f32x2 __attribute__((ext_vector_type(2)));
typedef float f32x4 __attribute__((ext_vector_type(4)));

__device__ __forceinline__ void gload16(const void* g, void* l) {
    __builtin_amdgcn_global_load_lds(
        (const __attribute__((address_space(1))) unsigned int*)g,
        (__attribute__((address_space(3))) unsigned int*)l, 16, 0, 0);
}

// ---- prep: W0/W1 split to [128][K] f16 hi/lo + degree count (fused) --------
__global__ void prep(const float* __restrict__ W0, const float* __restrict__ W1,
                     f16* __restrict__ Wth0, f16* __restrict__ Wtl0,
                     f16* __restrict__ Wth1, f16* __restrict__ Wtl1,
                     const int* __restrict__ dsts, int* __restrict__ deg, int E) {
    int i = blockIdx.x * blockDim.x + threadIdx.x;
    if (i < 256 * 128) {
        int k = i >> 7, c = i & 127;
        float v = W0[i];
        f16 h = (f16)v;
        Wth0[(size_t)c * 256 + k] = h;
        Wtl0[(size_t)c * 256 + k] = (f16)(v - (float)h);
    } else if (i < 256 * 128 + 128 * 128) {
        int j = i - 256 * 128;
        int k = j >> 7, c = j & 127;
        float v = W1[j];
        f16 h = (f16)v;
        Wth1[(size_t)c * 128 + k] = h;
        Wtl1[(size_t)c * 128 + k] = (f16)(v - (float)h);
    } else {
        int e = i - (256 * 128 + 128 * 128);
        if (e < E) atomicAdd(&deg[dsts[e]], 1);
    }
}

// ---------------- GEMM: Y16 = fp16(X @ W), fused el/er epilogue --------------
// AFP16=0: X f32 staged direct-to-LDS [128][32] f32 with granule XOR swizzle;
//          hi/lo fp16 split at frag read -> 3 MFMA passes.
// AFP16=1: X f16 staged direct [128][32] -> 2 MFMA passes.
// B staged [128][32] f16 linear; LDS row r holds phys col p=((r&15)<<3)|(r>>4)
// (source-side permutation), so lane lr owns phys cols lr*8..lr*8+7 in the
// epilogue -> packed f16x8 store + el/er via 16 fma + shfl_xor(1,2).
template <int AFP16>
__global__ __launch_bounds__(256, 2) void gemm_mfma(
        const void* __restrict__ Xv, const f16* __restrict__ Wth,
        const f16* __restrict__ Wtl, f16* __restrict__ Y16,
        const float* __restrict__ al, const float* __restrict__ ar,
        float* __restrict__ el_out, float* __restrict__ er_out,
        int nrows, int K) {
    __shared__ float As32[AFP16 ? 1 : 128 * 32];  // 16 KB (L0 only)
    __shared__ f16   As16[AFP16 ? 128 * 32 : 1];  // 8 KB (L1 only)
    __shared__ f16   Bh[128 * 32];                // 8 KB
    __shared__ f16   Bl[128 * 32];                // 8 KB
    const int t    = threadIdx.x;
    const int wave = t >> 6;
    const int lane = t & 63;
    const int lr   = lane & 15;   // frag row (A) / col (B,D)
    const int kg   = lane >> 4;   // k-group 0..3
    const int row0 = blockIdx.x * 128;

    f32x4 acc[2][8];
    #pragma unroll
    for (int i = 0; i < 2; ++i)
        #pragma unroll
        for (int j = 0; j < 8; ++j) acc[i][j] = (f32x4){0.f, 0.f, 0.f, 0.f};

    for (int k0 = 0; k0 < K; k0 += 32) {
        // ---- stage A (direct to LDS) ----
        if constexpr (!AFP16) {
            // [128][32] f32: 1024 granules of 16B; slot = g ^ (row&7)
            #pragma unroll
            for (int j = 0; j < 4; ++j) {
                int G = t + 256 * j;
                int row = G >> 3, slot = G & 7;
                int g = slot ^ (row & 7);
                int grow = row0 + row; if (grow >= nrows) grow = nrows - 1;
                gload16((const float*)Xv + (size_t)grow * K + k0 + g * 4,
                        &As32[G * 4]);
            }
        } else {
            // [128][32] f16 linear: 512 granules
            #pragma unroll
            for (int j = 0; j < 2; ++j) {
                int G = t + 256 * j;
                int row = G >> 2, g4 = G & 3;
                int grow = row0 + row; if (grow >= nrows) grow = nrows - 1;
                gload16((const f16*)Xv + (size_t)grow * K + k0 + g4 * 8,
                        &As16[G * 8]);
            }
        }
        // ---- stage B hi/lo (direct, permuted source) ----
        #pragma unroll
        for (int j = 0; j < 2; ++j) {
            int G = t + 256 * j;
            int r = G >> 2, g4 = G & 3;
            int p = ((r & 15) << 3) | (r >> 4);
            gload16(Wth + (size_t)p * K + k0 + g4 * 8, &Bh[G * 8]);
            gload16(Wtl + (size_t)p * K + k0 + g4 * 8, &Bl[G * 8]);
        }
        __syncthreads();   // compiler drains vmcnt before barrier

        // ---- fragments ----
        const int ar0_ = wave * 32 + lr;   // (arow&7) == (lr&7) for both frags
        f16x8 ah0, ah1, alo0, alo1;
        if constexpr (!AFP16) {
            int s0 = (2 * kg) ^ (lr & 7);
            int s1 = (2 * kg + 1) ^ (lr & 7);
            f32x4 u0 = *(const f32x4*)&As32[ar0_ * 32 + s0 * 4];
            f32x4 u1 = *(const f32x4*)&As32[ar0_ * 32 + s1 * 4];
            f32x4 v0 = *(const f32x4*)&As32[(ar0_ + 16) * 32 + s0 * 4];
            f32x4 v1 = *(const f32x4*)&As32[(ar0_ + 16) * 32 + s1 * 4];
            float a8[8] = {u0[0], u0[1], u0[2], u0[3], u1[0], u1[1], u1[2], u1[3]};
            float b8[8] = {v0[0], v0[1], v0[2], v0[3], v1[0], v1[1], v1[2], v1[3]};
            #pragma unroll
            for (int i = 0; i < 8; ++i) {
                f16 h0 = (f16)a8[i]; ah0[i] = h0; alo0[i] = (f16)(a8[i] - (float)h0);
                f16 h1 = (f16)b8[i]; ah1[i] = h1; alo1[i] = (f16)(b8[i] - (float)h1);
            }
        } else {
            ah0 = *(const f16x8*)&As16[ar0_ * 32 + kg * 8];
            ah1 = *(const f16x8*)&As16[(ar0_ + 16) * 32 + kg * 8];
        }
        f16x8 bh[8];
        #pragma unroll
        for (int cb = 0; cb < 8; ++cb)
            bh[cb] = *(const f16x8*)&Bh[(cb * 16 + lr) * 32 + kg * 8];

        // pass 1: Ah @ Wh
        #pragma unroll
        for (int cb = 0; cb < 8; ++cb) {
            acc[0][cb] = __builtin_amdgcn_mfma_f32_16x16x32_f16(ah0, bh[cb], acc[0][cb], 0, 0, 0);
            acc[1][cb] = __builtin_amdgcn_mfma_f32_16x16x32_f16(ah1, bh[cb], acc[1][cb], 0, 0, 0);
        }
        // pass 2: Al @ Wh (f32-A only)
        if constexpr (!AFP16) {
            #pragma unroll
            for (int cb = 0; cb < 8; ++cb) {
                acc[0][cb] = __builtin_amdgcn_mfma_f32_16x16x32_f16(alo0, bh[cb], acc[0][cb], 0, 0, 0);
                acc[1][cb] = __builtin_amdgcn_mfma_f32_16x16x32_f16(alo1, bh[cb], acc[1][cb], 0, 0, 0);
            }
        }
        // pass 3: Ah @ Wl (Wl streamed)
        #pragma unroll
        for (int cb = 0; cb < 8; ++cb) {
            f16x8 bl = *(const f16x8*)&Bl[(cb * 16 + lr) * 32 + kg * 8];
            acc[0][cb] = __builtin_amdgcn_mfma_f32_16x16x32_f16(ah0, bl, acc[0][cb], 0, 0, 0);
            acc[1][cb] = __builtin_amdgcn_mfma_f32_16x16x32_f16(ah1, bl, acc[1][cb], 0, 0, 0);
        }
        __syncthreads();
    }

    // ---- epilogue: store f16 row chunks + fused el/er ----
    const int hh = lr >> 2;
    const int co = (lr & 3) * 8;
    float alv[8], arv[8];
    #pragma unroll
    for (int j = 0; j < 8; ++j) {
        alv[j] = al[hh * 32 + co + j];
        arv[j] = ar[hh * 32 + co + j];
    }
    #pragma unroll
    for (int rb = 0; rb < 2; ++rb) {
        int rbase = row0 + wave * 32 + rb * 16 + kg * 4;
        #pragma unroll
        for (int r = 0; r < 4; ++r) {
            int grow = rbase + r;
            f16x8 hv;
            float sl_ = 0.0f, sr_ = 0.0f;
            #pragma unroll
            for (int cb = 0; cb < 8; ++cb) {
                float v = acc[rb][cb][r];
                hv[cb] = (f16)v;
                sl_ += v * alv[cb];
                sr_ += v * arv[cb];
            }
            sl_ += __shfl_xor(sl_, 1); sl_ += __shfl_xor(sl_, 2);
            sr_ += __shfl_xor(sr_, 1); sr_ += __shfl_xor(sr_, 2);
            if (grow < nrows) {
                *(f16x8*)(Y16 + (size_t)grow * 128 + lr * 8) = hv;
                if ((lane & 3) == 0) {
                    el_out[4 * (size_t)grow + hh] = sl_;
                    er_out[4 * (size_t)grow + hh] = sr_;
                }
            }
        }
    }
}

// ---------------- CSR scan ----------------
__global__ __launch_bounds__(256) void scan_block(const int* __restrict__ deg,
                                                  int* __restrict__ excl,
                                                  int* __restrict__ bsums, int n) {
    __shared__ int wsums[4];
    int t = threadIdx.x;
    int base = blockIdx.x * 1024;
    int idx = base + t * 4;
    int v[4];
    #pragma unroll
    for (int i = 0; i < 4; ++i) v[i] = (idx + i < n) ? deg[idx + i] : 0;
    int tsum = v[0] + v[1] + v[2] + v[3];
    int lane = t & 63, wid = t >> 6;
    int incl = tsum;
    #pragma unroll
    for (int off = 1; off < 64; off <<= 1) {
        int u = __shfl_up(incl, off, 64);
        if (lane >= off) incl += u;
    }
    if (lane == 63) wsums[wid] = incl;
    __syncthreads();
    if (t == 0) {
        int s = 0;
        #pragma unroll
        for (int w = 0; w < 4; ++w) { int x = wsums[w]; wsums[w] = s; s += x; }
    }
    __syncthreads();
    int ex = incl - tsum + wsums[wid];
    int run = ex;
    #pragma unroll
    for (int i = 0; i < 4; ++i) { if (idx + i < n) excl[idx + i] = run; run += v[i]; }
    if (t == 255) bsums[blockIdx.x] = ex + tsum;
}

// fused scan_sums + finalize: each block re-reduces bsums[0..b) locally.
__global__ __launch_bounds__(256) void scan_fin(int* __restrict__ row_off,
                                                const int* __restrict__ bsums,
                                                int* __restrict__ cursor,
                                                int n, int nb) {
    __shared__ int spfx;
    int b = blockIdx.x;
    int t = threadIdx.x;
    if (t < 64) {
        int v = 0;
        if (t < b && t < nb) v = bsums[t];
        int t2 = t + 64;
        if (t2 < b && t2 < nb) v += bsums[t2];
        #pragma unroll
        for (int off = 32; off; off >>= 1) v += __shfl_xor(v, off, 64);
        if (t == 0) spfx = v;
    }
    __syncthreads();
    int pfx = spfx;
    int base = b * 1024 + t * 4;
    #pragma unroll
    for (int i2 = 0; i2 < 4; ++i2) {
        int i = base + i2;
        if (i < n) {
            int v = row_off[i] + pfx;
            row_off[i] = v;
            cursor[i]  = v;
        }
    }
}

// ---------------- fused: CSR fill + layer-0 edge scores (atten0) ------------
__global__ void fill_csr_edge0(const int* __restrict__ srcs, const int* __restrict__ dsts,
                               int* __restrict__ cursor, int* __restrict__ csr_src,
                               const float* __restrict__ el, const float* __restrict__ er,
                               float* __restrict__ atten0, int E) {
    int e = blockIdx.x * blockDim.x + threadIdx.x;
    if (e >= E) return;
    int s = srcs[e], d = dsts[e];
    int p = atomicAdd(&cursor[d], 1);
    csr_src[p] = s;
    float4 elv = *(const float4*)(el + 4 * (size_t)s);
    float4 erv = *(const float4*)(er + 4 * (size_t)d);
    float v0 = elv.x + erv.x, v1 = elv.y + erv.y;
    float v2 = elv.z + erv.z, v3 = elv.w + erv.w;
    v0 = v0 > 0.0f ? v0 : 0.2f * v0;
    v1 = v1 > 0.0f ? v1 : 0.2f * v1;
    v2 = v2 > 0.0f ? v2 : 0.2f * v2;
    v3 = v3 > 0.0f ? v3 : 0.2f * v3;
    __builtin_nontemporal_store((v0 + v1 + v2 + v3) * 0.25f, atten0 + e);
}

// ---------------- layer-1 edge pass: e1 + atten1 only -----------------------
__global__ void edge1_kernel(const int* __restrict__ srcs, const int* __restrict__ dsts,
                             const float* __restrict__ el, const float* __restrict__ er,
                             float* __restrict__ e1_out, float* __restrict__ atten1,
                             int E) {
    int e = blockIdx.x * blockDim.x + threadIdx.x;
    if (e >= E) return;
    int s = srcs[e], d = dsts[e];
    float4 elv = *(const float4*)(el + 4 * (size_t)s);
    float4 erv = *(const float4*)(er + 4 * (size_t)d);
    float v0 = elv.x + erv.x, v1 = elv.y + erv.y;
    float v2 = elv.z + erv.z, v3 = elv.w + erv.w;
    v0 = v0 > 0.0f ? v0 : 0.2f * v0;
    v1 = v1 > 0.0f ? v1 : 0.2f * v1;
    v2 = v2 > 0.0f ? v2 : 0.2f * v2;
    v3 = v3 > 0.0f ? v3 : 0.2f * v3;
    __builtin_nontemporal_store((f32x4){v0, v1, v2, v3},
                                (f32x4*)(e1_out + 4 * (size_t)e));
    __builtin_nontemporal_store((v0 + v1 + v2 + v3) * 0.25f, atten1 + e);
}

// ---------------- gather aggregation: one wave per dst node -----------------
template <int LAYER>
__global__ __launch_bounds__(256) void aggregate(const int* __restrict__ row_off,
                                                 const int* __restrict__ deg,
                                                 const int* __restrict__ csr_src,
                                                 const float* __restrict__ el,
                                                 const float* __restrict__ er,
                                                 const f16* __restrict__ feat16,
                                                 const f16* __restrict__ resid16,
                                                 f16* __restrict__ out16,
                                                 float* __restrict__ out32,
                                                 float* __restrict__ heads,
                                                 int N) {
    int wave = (blockIdx.x * 256 + threadIdx.x) >> 6;
    if (wave >= N) return;
    int lane = threadIdx.x & 63;
    int q  = lane >> 4;          // edge phase 0..3
    int sc = lane & 15;          // col slot: cols sc*8 .. sc*8+7
    int h  = sc >> 2;            // head of these cols
    int start = row_off[wave];
    int dc    = deg[wave];
    float er_h = er[4 * (size_t)wave + h];

    float acc[8];
    #pragma unroll
    for (int j = 0; j < 8; ++j) acc[j] = 0.0f;
    float dh = 0.0f;

    for (int cs = 0; cs < dc; cs += 64) {
        int act = dc - cs; if (act > 64) act = 64;
        int sl = (lane < act) ? csr_src[start + cs + lane] : 0;
        int i = 0;
        for (; i + 8 <= act; i += 8) {
            int s0 = __shfl(sl, i + q);
            int s1 = __shfl(sl, i + 4 + q);
            float x0 = el[4 * (size_t)s0 + h] + er_h;
            float x1 = el[4 * (size_t)s1 + h] + er_h;
            x0 = x0 > 0.0f ? x0 : 0.2f * x0;
            x1 = x1 > 0.0f ? x1 : 0.2f * x1;
            float w0 = __expf(x0);
            float w1 = __expf(x1);
            f16x8 f0 = *(const f16x8*)(feat16 + 128 * (size_t)s0 + sc * 8);
            f16x8 f1 = *(const f16x8*)(feat16 + 128 * (size_t)s1 + sc * 8);
            #pragma unroll
            for (int j = 0; j < 8; ++j) acc[j] += w0 * (float)f0[j];
            #pragma unroll
            for (int j = 0; j < 8; ++j) acc[j] += w1 * (float)f1[j];
            dh += w0 + w1;
        }
        for (; i < act; i += 4) {
            int e = i + q;
            bool on = e < act;
            int s = __shfl(sl, on ? e : 0);
            float x = el[4 * (size_t)s + h] + er_h;
            x = x > 0.0f ? x : 0.2f * x;
            float w = on ? __expf(x) : 0.0f;
            f16x8 fv = *(const f16x8*)(feat16 + 128 * (size_t)s + sc * 8);
            #pragma unroll
            for (int j = 0; j < 8; ++j) acc[j] += w * (float)fv[j];
            dh += w;
        }
    }

    #pragma unroll
    for (int j = 0; j < 8; ++j) {
        acc[j] += __shfl_xor(acc[j], 16);
        acc[j] += __shfl_xor(acc[j], 32);
    }
    dh += __shfl_xor(dh, 16);
    dh += __shfl_xor(dh, 32);

    float inv = (dc > 0) ? 1.0f / dh : 0.0f;
    float ax = (q == 0) ? acc[0] : (q == 1) ? acc[2] : (q == 2) ? acc[4] : acc[6];
    float ay = (q == 0) ? acc[1] : (q == 1) ? acc[3] : (q == 2) ? acc[5] : acc[7];
    ax *= inv; ay *= inv;
    int c0 = sc * 8 + q * 2;
    size_t o = 128 * (size_t)wave + c0;
    if (LAYER == 1) {
        f16x2 rv = *(const f16x2*)(resid16 + o);
        ax += (float)rv[0]; ay += (float)rv[1];
    }
    ax = ax > 0.0f ? ax : __expf(ax) - 1.0f;
    ay = ay > 0.0f ? ay : __expf(ay) - 1.0f;
    if (LAYER == 0) {
        f16x2 hv; hv[0] = (f16)ax; hv[1] = (f16)ay;
        *(f16x2*)(out16 + o) = hv;
    } else {
        __builtin_nontemporal_store((f32x2){ax, ay}, (f32x2*)(out32 + o));
        __builtin_nontemporal_store(
            (f32x2){ax, ay},
            (f32x2*)(heads + (size_t)h * N * 32 + (size_t)wave * 32 + (c0 & 31)));
    }
}

extern "C" void kernel_launch(void* const* d_in, const int* in_sizes, int n_in,
                              void* d_out, int out_size, void* d_ws, size_t ws_size,
                              hipStream_t stream) {
    const float* x   = (const float*)d_in[0];
    const int*   ei  = (const int*)d_in[1];
    const float* W0  = (const float*)d_in[2];
    const float* al0 = (const float*)d_in[3];
    const float* ar0 = (const float*)d_in[4];
    const float* W1  = (const float*)d_in[5];
    const float* al1 = (const float*)d_in[6];
    const float* ar1 = (const float*)d_in[7];

    const int N = in_sizes[0] / 256;     // 100000
    const int E = in_sizes[1] / 2;       // 800000
    const size_t NF = (size_t)N * 128;

    const int* srcs = ei;
    const int* dsts = ei + E;

    float* out = (float*)d_out;
    f16*   f16ws  = (f16*)d_ws;
    f16*   feat16 = f16ws;                               // N*128 f16
    f16*   h1_16  = feat16 + NF;                         // N*128 f16
    float* el   = (float*)(h1_16 + NF);                  // N*4
    float* er   = el + (size_t)N * 4;                    // N*4
    f16*   wth0 = (f16*)(er + (size_t)N * 4);            // 128*256
    f16*   wtl0 = wth0 + (size_t)128 * 256;              // 128*256
    f16*   wth1 = wtl0 + (size_t)128 * 256;              // 128*128
    f16*   wtl1 = wth1 + (size_t)128 * 128;              // 128*128
    int*   ints    = (int*)(wtl1 + (size_t)128 * 128);
    int*   deg     = ints;                               // N
    int*   row_off = deg + N;                            // N
    int*   cursor  = row_off + N;                        // N
    int*   csr_src = cursor + N;                         // E
    int*   bsums   = csr_src + E;                        // <=256

    float* heads      = out + NF;
    float* e1_out     = out + 2 * NF;
    float* atten0_out = e1_out + (size_t)E * 4;
    float* atten1_out = atten0_out + E;

    // ---- prep: weight split + degree count (one launch) ----
    hipMemsetAsync(deg, 0, (size_t)N * sizeof(int), stream);
    const int wtot = 256 * 128 + 128 * 128;
    prep<<<(wtot + E + 255) / 256, 256, 0, stream>>>(W0, W1, wth0, wtl0, wth1, wtl1,
                                                     dsts, deg, E);
    int nb = (N + 1023) / 1024;
    scan_block<<<nb, 256, 0, stream>>>(deg, row_off, bsums, N);
    scan_fin<<<nb, 256, 0, stream>>>(row_off, bsums, cursor, N, nb);

    const int gemm_blocks = (N + 127) / 128;
    const int agg_blocks  = (N + 3) / 4;

    // ---- layer 0 ----
    gemm_mfma<0><<<gemm_blocks, 256, 0, stream>>>(x, wth0, wtl0, feat16, al0, ar0,
                                                  el, er, N, 256);
    fill_csr_edge0<<<(E + 255) / 256, 256, 0, stream>>>(srcs, dsts, cursor, csr_src,
                                                        el, er, atten0_out, E);
    aggregate<0><<<agg_blocks, 256, 0, stream>>>(row_off, deg, csr_src, el, er,
                                                 feat16, nullptr, h1_16, nullptr,
                                                 nullptr, N);

    // ---- layer 1 ----
    gemm_mfma<1><<<gemm_blocks, 256, 0, stream>>>(h1_16, wth1, wtl1, feat16, al1, ar1,
                                                  el, er, N, 128);
    edge1_kernel<<<(E + 255) / 256, 256, 0, stream>>>(srcs, dsts, el, er,
                                                      e1_out, atten1_out, E);
    aggregate<1><<<agg_blocks, 256, 0, stream>>>(row_off, deg, csr_src, el, er,
                                                 feat16, h1_16, nullptr, out,
                                                 heads, N);
}

// Round 6
// 416.242 us; speedup vs baseline: 1.5860x; 1.0259x over previous
//
#include <hip/hip_runtime.h>
#include <hip/hip_bf16.h>

// GAT 2-layer forward for MI355X (gfx950). Round 9: serialization round.
// - scan_block merged into the gemm0 launch (blocks >= gemm_blocks do the scan;
//   it only gates fill_csr_edge0 which also needs gemm0's el/er).
// - edge1 merged into the aggregate<1> launch (independent, both gated by gemm1;
//   memory-light edge blocks backfill CUs under the gather waves).
// - row_off has N+1 entries (sentinel=E): aggregate loads start/end from one
//   cache line instead of separate row_off+deg arrays.
// 7 launches + 1 memset. All math bit-identical to round 8.
//
// d_out (floats): temp[N*128] | heads[4][N*32] | e1[E*4] | atten0[E] | atten1[E]
// Workspace: feat16(N*128 f16) | h1_16(N*128 f16) | el(N*4) | er(N*4) |
//            wth0/wtl0/wth1/wtl1 | ints: deg(N) row_off(N+1) cursor(N)
//            csr_src(E) bsums(256)

typedef _Float16 f16;
typedef _Float16 f16x2 __attribute__((ext_vector_type(2)));
typedef _Float16 f16x8 __attribute__((ext_vector_type(8)));
typedef float f32x2 __attribute__((ext_vector_type(2)));
typedef float f32x4 __attribute__((ext_vector_type(4)));

__device__ __forceinline__ void gload16(const void* g, void* l) {
    __builtin_amdgcn_global_load_lds(
        (const __attribute__((address_space(1))) unsigned int*)g,
        (__attribute__((address_space(3))) unsigned int*)l, 16, 0, 0);
}

// ---- prep: W0/W1 split to [128][K] f16 hi/lo + degree count (fused) --------
__global__ void prep(const float* __restrict__ W0, const float* __restrict__ W1,
                     f16* __restrict__ Wth0, f16* __restrict__ Wtl0,
                     f16* __restrict__ Wth1, f16* __restrict__ Wtl1,
                     const int* __restrict__ dsts, int* __restrict__ deg, int E) {
    int i = blockIdx.x * blockDim.x + threadIdx.x;
    if (i < 256 * 128) {
        int k = i >> 7, c = i & 127;
        float v = W0[i];
        f16 h = (f16)v;
        Wth0[(size_t)c * 256 + k] = h;
        Wtl0[(size_t)c * 256 + k] = (f16)(v - (float)h);
    } else if (i < 256 * 128 + 128 * 128) {
        int j = i - 256 * 128;
        int k = j >> 7, c = j & 127;
        float v = W1[j];
        f16 h = (f16)v;
        Wth1[(size_t)c * 128 + k] = h;
        Wtl1[(size_t)c * 128 + k] = (f16)(v - (float)h);
    } else {
        int e = i - (256 * 128 + 128 * 128);
        if (e < E) atomicAdd(&deg[dsts[e]], 1);
    }
}

// ---------------- GEMM body: Y16 = fp16(X @ W), fused el/er epilogue ---------
// AFP16=0: X f32 staged direct-to-LDS [128][32] f32, granule XOR swizzle
//          (slot = g ^ (row&7)); hi/lo split at frag read -> 3 MFMA passes.
// AFP16=1: X f16 staged direct [128][32] -> 2 MFMA passes.
// B staged [128][32] f16 linear; LDS row r holds phys col p=((r&15)<<3)|(r>>4),
// so lane lr owns phys cols lr*8..lr*8+7 -> packed f16x8 store + el/er via
// 16 fma + shfl_xor(1,2).
template <int AFP16>
__device__ __forceinline__ void gemm_body(
        int bid, const void* __restrict__ Xv, const f16* __restrict__ Wth,
        const f16* __restrict__ Wtl, f16* __restrict__ Y16,
        const float* __restrict__ al, const float* __restrict__ ar,
        float* __restrict__ el_out, float* __restrict__ er_out,
        int nrows, int K) {
    __shared__ float As32[AFP16 ? 1 : 128 * 32];  // 16 KB (L0 only)
    __shared__ f16   As16[AFP16 ? 128 * 32 : 1];  // 8 KB (L1 only)
    __shared__ f16   Bh[128 * 32];                // 8 KB
    __shared__ f16   Bl[128 * 32];                // 8 KB
    const int t    = threadIdx.x;
    const int wave = t >> 6;
    const int lane = t & 63;
    const int lr   = lane & 15;   // frag row (A) / col (B,D)
    const int kg   = lane >> 4;   // k-group 0..3
    const int row0 = bid * 128;

    f32x4 acc[2][8];
    #pragma unroll
    for (int i = 0; i < 2; ++i)
        #pragma unroll
        for (int j = 0; j < 8; ++j) acc[i][j] = (f32x4){0.f, 0.f, 0.f, 0.f};

    for (int k0 = 0; k0 < K; k0 += 32) {
        // ---- stage A (direct to LDS) ----
        if constexpr (!AFP16) {
            #pragma unroll
            for (int j = 0; j < 4; ++j) {
                int G = t + 256 * j;
                int row = G >> 3, slot = G & 7;
                int g = slot ^ (row & 7);
                int grow = row0 + row; if (grow >= nrows) grow = nrows - 1;
                gload16((const float*)Xv + (size_t)grow * K + k0 + g * 4,
                        &As32[G * 4]);
            }
        } else {
            #pragma unroll
            for (int j = 0; j < 2; ++j) {
                int G = t + 256 * j;
                int row = G >> 2, g4 = G & 3;
                int grow = row0 + row; if (grow >= nrows) grow = nrows - 1;
                gload16((const f16*)Xv + (size_t)grow * K + k0 + g4 * 8,
                        &As16[G * 8]);
            }
        }
        // ---- stage B hi/lo (direct, permuted source) ----
        #pragma unroll
        for (int j = 0; j < 2; ++j) {
            int G = t + 256 * j;
            int r = G >> 2, g4 = G & 3;
            int p = ((r & 15) << 3) | (r >> 4);
            gload16(Wth + (size_t)p * K + k0 + g4 * 8, &Bh[G * 8]);
            gload16(Wtl + (size_t)p * K + k0 + g4 * 8, &Bl[G * 8]);
        }
        __syncthreads();   // compiler drains vmcnt before barrier

        // ---- fragments ----
        const int ar0_ = wave * 32 + lr;
        f16x8 ah0, ah1, alo0, alo1;
        if constexpr (!AFP16) {
            int s0 = (2 * kg) ^ (lr & 7);
            int s1 = (2 * kg + 1) ^ (lr & 7);
            f32x4 u0 = *(const f32x4*)&As32[ar0_ * 32 + s0 * 4];
            f32x4 u1 = *(const f32x4*)&As32[ar0_ * 32 + s1 * 4];
            f32x4 v0 = *(const f32x4*)&As32[(ar0_ + 16) * 32 + s0 * 4];
            f32x4 v1 = *(const f32x4*)&As32[(ar0_ + 16) * 32 + s1 * 4];
            float a8[8] = {u0[0], u0[1], u0[2], u0[3], u1[0], u1[1], u1[2], u1[3]};
            float b8[8] = {v0[0], v0[1], v0[2], v0[3], v1[0], v1[1], v1[2], v1[3]};
            #pragma unroll
            for (int i = 0; i < 8; ++i) {
                f16 h0 = (f16)a8[i]; ah0[i] = h0; alo0[i] = (f16)(a8[i] - (float)h0);
                f16 h1 = (f16)b8[i]; ah1[i] = h1; alo1[i] = (f16)(b8[i] - (float)h1);
            }
        } else {
            ah0 = *(const f16x8*)&As16[ar0_ * 32 + kg * 8];
            ah1 = *(const f16x8*)&As16[(ar0_ + 16) * 32 + kg * 8];
        }
        f16x8 bh[8];
        #pragma unroll
        for (int cb = 0; cb < 8; ++cb)
            bh[cb] = *(const f16x8*)&Bh[(cb * 16 + lr) * 32 + kg * 8];

        // pass 1: Ah @ Wh
        #pragma unroll
        for (int cb = 0; cb < 8; ++cb) {
            acc[0][cb] = __builtin_amdgcn_mfma_f32_16x16x32_f16(ah0, bh[cb], acc[0][cb], 0, 0, 0);
            acc[1][cb] = __builtin_amdgcn_mfma_f32_16x16x32_f16(ah1, bh[cb], acc[1][cb], 0, 0, 0);
        }
        // pass 2: Al @ Wh (f32-A only)
        if constexpr (!AFP16) {
            #pragma unroll
            for (int cb = 0; cb < 8; ++cb) {
                acc[0][cb] = __builtin_amdgcn_mfma_f32_16x16x32_f16(alo0, bh[cb], acc[0][cb], 0, 0, 0);
                acc[1][cb] = __builtin_amdgcn_mfma_f32_16x16x32_f16(alo1, bh[cb], acc[1][cb], 0, 0, 0);
            }
        }
        // pass 3: Ah @ Wl (Wl streamed)
        #pragma unroll
        for (int cb = 0; cb < 8; ++cb) {
            f16x8 bl = *(const f16x8*)&Bl[(cb * 16 + lr) * 32 + kg * 8];
            acc[0][cb] = __builtin_amdgcn_mfma_f32_16x16x32_f16(ah0, bl, acc[0][cb], 0, 0, 0);
            acc[1][cb] = __builtin_amdgcn_mfma_f32_16x16x32_f16(ah1, bl, acc[1][cb], 0, 0, 0);
        }
        __syncthreads();
    }

    // ---- epilogue: store f16 row chunks + fused el/er ----
    const int hh = lr >> 2;
    const int co = (lr & 3) * 8;
    float alv[8], arv[8];
    #pragma unroll
    for (int j = 0; j < 8; ++j) {
        alv[j] = al[hh * 32 + co + j];
        arv[j] = ar[hh * 32 + co + j];
    }
    #pragma unroll
    for (int rb = 0; rb < 2; ++rb) {
        int rbase = row0 + wave * 32 + rb * 16 + kg * 4;
        #pragma unroll
        for (int r = 0; r < 4; ++r) {
            int grow = rbase + r;
            f16x8 hv;
            float sl_ = 0.0f, sr_ = 0.0f;
            #pragma unroll
            for (int cb = 0; cb < 8; ++cb) {
                float v = acc[rb][cb][r];
                hv[cb] = (f16)v;
                sl_ += v * alv[cb];
                sr_ += v * arv[cb];
            }
            sl_ += __shfl_xor(sl_, 1); sl_ += __shfl_xor(sl_, 2);
            sr_ += __shfl_xor(sr_, 1); sr_ += __shfl_xor(sr_, 2);
            if (grow < nrows) {
                *(f16x8*)(Y16 + (size_t)grow * 128 + lr * 8) = hv;
                if ((lane & 3) == 0) {
                    el_out[4 * (size_t)grow + hh] = sl_;
                    er_out[4 * (size_t)grow + hh] = sr_;
                }
            }
        }
    }
}

// ---------------- CSR block scan body ----------------
__device__ __forceinline__ void scan_body(int b, const int* __restrict__ deg,
                                          int* __restrict__ excl,
                                          int* __restrict__ bsums, int n) {
    __shared__ int wsums[4];
    int t = threadIdx.x;
    int base = b * 1024;
    int idx = base + t * 4;
    int v[4];
    #pragma unroll
    for (int i = 0; i < 4; ++i) v[i] = (idx + i < n) ? deg[idx + i] : 0;
    int tsum = v[0] + v[1] + v[2] + v[3];
    int lane = t & 63, wid = t >> 6;
    int incl = tsum;
    #pragma unroll
    for (int off = 1; off < 64; off <<= 1) {
        int u = __shfl_up(incl, off, 64);
        if (lane >= off) incl += u;
    }
    if (lane == 63) wsums[wid] = incl;
    __syncthreads();
    if (t == 0) {
        int s = 0;
        #pragma unroll
        for (int w = 0; w < 4; ++w) { int x = wsums[w]; wsums[w] = s; s += x; }
    }
    __syncthreads();
    int ex = incl - tsum + wsums[wid];
    int run = ex;
    #pragma unroll
    for (int i = 0; i < 4; ++i) { if (idx + i < n) excl[idx + i] = run; run += v[i]; }
    if (t == 255) bsums[b] = ex + tsum;
}

// gemm layer-0 + CSR block-scan in one launch (scan only gates fill_csr_edge0,
// which also needs this kernel's el/er)
__global__ __launch_bounds__(256, 2) void gemm0_scan(
        const float* __restrict__ X, const f16* __restrict__ Wth,
        const f16* __restrict__ Wtl, f16* __restrict__ Y16,
        const float* __restrict__ al, const float* __restrict__ ar,
        float* __restrict__ el_out, float* __restrict__ er_out,
        int nrows, int K, int gblocks,
        const int* __restrict__ deg, int* __restrict__ excl,
        int* __restrict__ bsums, int n) {
    if ((int)blockIdx.x < gblocks)
        gemm_body<0>(blockIdx.x, X, Wth, Wtl, Y16, al, ar, el_out, er_out, nrows, K);
    else
        scan_body(blockIdx.x - gblocks, deg, excl, bsums, n);
}

__global__ __launch_bounds__(256, 2) void gemm_mfma1(
        const f16* __restrict__ X, const f16* __restrict__ Wth,
        const f16* __restrict__ Wtl, f16* __restrict__ Y16,
        const float* __restrict__ al, const float* __restrict__ ar,
        float* __restrict__ el_out, float* __restrict__ er_out,
        int nrows, int K) {
    gemm_body<1>(blockIdx.x, X, Wth, Wtl, Y16, al, ar, el_out, er_out, nrows, K);
}

// fused scan_sums + finalize; also writes row_off[n] = E sentinel.
__global__ __launch_bounds__(256) void scan_fin(int* __restrict__ row_off,
                                                const int* __restrict__ bsums,
                                                int* __restrict__ cursor,
                                                const int* __restrict__ deg,
                                                int n, int nb) {
    __shared__ int spfx;
    int b = blockIdx.x;
    int t = threadIdx.x;
    if (t < 64) {
        int v = 0;
        if (t < b && t < nb) v = bsums[t];
        int t2 = t + 64;
        if (t2 < b && t2 < nb) v += bsums[t2];
        #pragma unroll
        for (int off = 32; off; off >>= 1) v += __shfl_xor(v, off, 64);
        if (t == 0) spfx = v;
    }
    __syncthreads();
    int pfx = spfx;
    int base = b * 1024 + t * 4;
    #pragma unroll
    for (int i2 = 0; i2 < 4; ++i2) {
        int i = base + i2;
        if (i < n) {
            int v = row_off[i] + pfx;
            row_off[i] = v;
            cursor[i]  = v;
            if (i == n - 1) row_off[n] = v + deg[i];
        }
    }
}

// ---------------- fused: CSR fill + layer-0 edge scores (atten0) ------------
__global__ void fill_csr_edge0(const int* __restrict__ srcs, const int* __restrict__ dsts,
                               int* __restrict__ cursor, int* __restrict__ csr_src,
                               const float* __restrict__ el, const float* __restrict__ er,
                               float* __restrict__ atten0, int E) {
    int e = blockIdx.x * blockDim.x + threadIdx.x;
    if (e >= E) return;
    int s = srcs[e], d = dsts[e];
    int p = atomicAdd(&cursor[d], 1);
    csr_src[p] = s;
    float4 elv = *(const float4*)(el + 4 * (size_t)s);
    float4 erv = *(const float4*)(er + 4 * (size_t)d);
    float v0 = elv.x + erv.x, v1 = elv.y + erv.y;
    float v2 = elv.z + erv.z, v3 = elv.w + erv.w;
    v0 = v0 > 0.0f ? v0 : 0.2f * v0;
    v1 = v1 > 0.0f ? v1 : 0.2f * v1;
    v2 = v2 > 0.0f ? v2 : 0.2f * v2;
    v3 = v3 > 0.0f ? v3 : 0.2f * v3;
    __builtin_nontemporal_store((v0 + v1 + v2 + v3) * 0.25f, atten0 + e);
}

// ---------------- layer-1 edge pass body ----------------
__device__ __forceinline__ void edge1_body(int bid,
        const int* __restrict__ srcs, const int* __restrict__ dsts,
        const float* __restrict__ el, const float* __restrict__ er,
        float* __restrict__ e1_out, float* __restrict__ atten1, int E) {
    int e = bid * 256 + threadIdx.x;
    if (e >= E) return;
    int s = srcs[e], d = dsts[e];
    float4 elv = *(const float4*)(el + 4 * (size_t)s);
    float4 erv = *(const float4*)(er + 4 * (size_t)d);
    float v0 = elv.x + erv.x, v1 = elv.y + erv.y;
    float v2 = elv.z + erv.z, v3 = elv.w + erv.w;
    v0 = v0 > 0.0f ? v0 : 0.2f * v0;
    v1 = v1 > 0.0f ? v1 : 0.2f * v1;
    v2 = v2 > 0.0f ? v2 : 0.2f * v2;
    v3 = v3 > 0.0f ? v3 : 0.2f * v3;
    __builtin_nontemporal_store((f32x4){v0, v1, v2, v3},
                                (f32x4*)(e1_out + 4 * (size_t)e));
    __builtin_nontemporal_store((v0 + v1 + v2 + v3) * 0.25f, atten1 + e);
}

// ---------------- gather aggregation body: one wave per dst node ------------
template <int LAYER>
__device__ __forceinline__ void agg_body(int bid,
        const int* __restrict__ row_off, const int* __restrict__ csr_src,
        const float* __restrict__ el, const float* __restrict__ er,
        const f16* __restrict__ feat16, const f16* __restrict__ resid16,
        f16* __restrict__ out16, float* __restrict__ out32,
        float* __restrict__ heads, int N) {
    int wave = (bid * 256 + (int)threadIdx.x) >> 6;
    if (wave >= N) return;
    int lane = threadIdx.x & 63;
    int q  = lane >> 4;          // edge phase 0..3
    int sc = lane & 15;          // col slot: cols sc*8 .. sc*8+7
    int h  = sc >> 2;            // head of these cols
    int start = row_off[wave];
    int dc    = row_off[wave + 1] - start;   // same cache line as start
    float er_h = er[4 * (size_t)wave + h];

    float acc[8];
    #pragma unroll
    for (int j = 0; j < 8; ++j) acc[j] = 0.0f;
    float dh = 0.0f;

    for (int cs = 0; cs < dc; cs += 64) {
        int act = dc - cs; if (act > 64) act = 64;
        int sl = (lane < act) ? csr_src[start + cs + lane] : 0;
        int i = 0;
        for (; i + 8 <= act; i += 8) {
            int s0 = __shfl(sl, i + q);
            int s1 = __shfl(sl, i + 4 + q);
            float x0 = el[4 * (size_t)s0 + h] + er_h;
            float x1 = el[4 * (size_t)s1 + h] + er_h;
            x0 = x0 > 0.0f ? x0 : 0.2f * x0;
            x1 = x1 > 0.0f ? x1 : 0.2f * x1;
            float w0 = __expf(x0);
            float w1 = __expf(x1);
            f16x8 f0 = *(const f16x8*)(feat16 + 128 * (size_t)s0 + sc * 8);
            f16x8 f1 = *(const f16x8*)(feat16 + 128 * (size_t)s1 + sc * 8);
            #pragma unroll
            for (int j = 0; j < 8; ++j) acc[j] += w0 * (float)f0[j];
            #pragma unroll
            for (int j = 0; j < 8; ++j) acc[j] += w1 * (float)f1[j];
            dh += w0 + w1;
        }
        for (; i < act; i += 4) {
            int e = i + q;
            bool on = e < act;
            int s = __shfl(sl, on ? e : 0);
            float x = el[4 * (size_t)s + h] + er_h;
            x = x > 0.0f ? x : 0.2f * x;
            float w = on ? __expf(x) : 0.0f;
            f16x8 fv = *(const f16x8*)(feat16 + 128 * (size_t)s + sc * 8);
            #pragma unroll
            for (int j = 0; j < 8; ++j) acc[j] += w * (float)fv[j];
            dh += w;
        }
    }

    #pragma unroll
    for (int j = 0; j < 8; ++j) {
        acc[j] += __shfl_xor(acc[j], 16);
        acc[j] += __shfl_xor(acc[j], 32);
    }
    dh += __shfl_xor(dh, 16);
    dh += __shfl_xor(dh, 32);

    float inv = (dc > 0) ? 1.0f / dh : 0.0f;
    float ax = (q == 0) ? acc[0] : (q == 1) ? acc[2] : (q == 2) ? acc[4] : acc[6];
    float ay = (q == 0) ? acc[1] : (q == 1) ? acc[3] : (q == 2) ? acc[5] : acc[7];
    ax *= inv; ay *= inv;
    int c0 = sc * 8 + q * 2;
    size_t o = 128 * (size_t)wave + c0;
    if (LAYER == 1) {
        f16x2 rv = *(const f16x2*)(resid16 + o);
        ax += (float)rv[0]; ay += (float)rv[1];
    }
    ax = ax > 0.0f ? ax : __expf(ax) - 1.0f;
    ay = ay > 0.0f ? ay : __expf(ay) - 1.0f;
    if (LAYER == 0) {
        f16x2 hv; hv[0] = (f16)ax; hv[1] = (f16)ay;
        *(f16x2*)(out16 + o) = hv;
    } else {
        __builtin_nontemporal_store((f32x2){ax, ay}, (f32x2*)(out32 + o));
        __builtin_nontemporal_store(
            (f32x2){ax, ay},
            (f32x2*)(heads + (size_t)h * N * 32 + (size_t)wave * 32 + (c0 & 31)));
    }
}

__global__ __launch_bounds__(256) void aggregate0(const int* __restrict__ row_off,
                                                  const int* __restrict__ csr_src,
                                                  const float* __restrict__ el,
                                                  const float* __restrict__ er,
                                                  const f16* __restrict__ feat16,
                                                  f16* __restrict__ out16, int N) {
    agg_body<0>(blockIdx.x, row_off, csr_src, el, er, feat16, nullptr,
                out16, nullptr, nullptr, N);
}

// aggregate<1> + edge1 in one launch (both gated only by gemm1; independent)
__global__ __launch_bounds__(256) void layer1_fused(
        const int* __restrict__ row_off, const int* __restrict__ csr_src,
        const float* __restrict__ el, const float* __restrict__ er,
        const f16* __restrict__ feat16, const f16* __restrict__ resid16,
        float* __restrict__ out32, float* __restrict__ heads,
        const int* __restrict__ srcs, const int* __restrict__ dsts,
        float* __restrict__ e1_out, float* __restrict__ atten1,
        int aggBlocks, int N, int E) {
    if ((int)blockIdx.x < aggBlocks)
        agg_body<1>(blockIdx.x, row_off, csr_src, el, er, feat16, resid16,
                    nullptr, out32, heads, N);
    else
        edge1_body(blockIdx.x - aggBlocks, srcs, dsts, el, er, e1_out, atten1, E);
}

extern "C" void kernel_launch(void* const* d_in, const int* in_sizes, int n_in,
                              void* d_out, int out_size, void* d_ws, size_t ws_size,
                              hipStream_t stream) {
    const float* x   = (const float*)d_in[0];
    const int*   ei  = (const int*)d_in[1];
    const float* W0  = (const float*)d_in[2];
    const float* al0 = (const float*)d_in[3];
    const float* ar0 = (const float*)d_in[4];
    const float* W1  = (const float*)d_in[5];
    const float* al1 = (const float*)d_in[6];
    const float* ar1 = (const float*)d_in[7];

    const int N = in_sizes[0] / 256;     // 100000
    const int E = in_sizes[1] / 2;       // 800000
    const size_t NF = (size_t)N * 128;

    const int* srcs = ei;
    const int* dsts = ei + E;

    float* out = (float*)d_out;
    f16*   f16ws  = (f16*)d_ws;
    f16*   feat16 = f16ws;                               // N*128 f16
    f16*   h1_16  = feat16 + NF;                         // N*128 f16
    float* el   = (float*)(h1_16 + NF);                  // N*4
    float* er   = el + (size_t)N * 4;                    // N*4
    f16*   wth0 = (f16*)(er + (size_t)N * 4);            // 128*256
    f16*   wtl0 = wth0 + (size_t)128 * 256;              // 128*256
    f16*   wth1 = wtl0 + (size_t)128 * 256;              // 128*128
    f16*   wtl1 = wth1 + (size_t)128 * 128;              // 128*128
    int*   ints    = (int*)(wtl1 + (size_t)128 * 128);
    int*   deg     = ints;                               // N
    int*   row_off = deg + N;                            // N+1 (sentinel)
    int*   cursor  = row_off + N + 1;                    // N
    int*   csr_src = cursor + N;                         // E
    int*   bsums   = csr_src + E;                        // <=256

    float* heads      = out + NF;
    float* e1_out     = out + 2 * NF;
    float* atten0_out = e1_out + (size_t)E * 4;
    float* atten1_out = atten0_out + E;

    // ---- prep: weight split + degree count (one launch) ----
    hipMemsetAsync(deg, 0, (size_t)N * sizeof(int), stream);
    const int wtot = 256 * 128 + 128 * 128;
    prep<<<(wtot + E + 255) / 256, 256, 0, stream>>>(W0, W1, wth0, wtl0, wth1, wtl1,
                                                     dsts, deg, E);

    const int gemm_blocks = (N + 127) / 128;
    const int agg_blocks  = (N + 3) / 4;
    const int edge_blocks = (E + 255) / 256;
    const int nb = (N + 1023) / 1024;

    // ---- layer 0: gemm + CSR block-scan in one launch ----
    gemm0_scan<<<gemm_blocks + nb, 256, 0, stream>>>(x, wth0, wtl0, feat16, al0, ar0,
                                                     el, er, N, 256, gemm_blocks,
                                                     deg, row_off, bsums, N);
    scan_fin<<<nb, 256, 0, stream>>>(row_off, bsums, cursor, deg, N, nb);
    fill_csr_edge0<<<edge_blocks, 256, 0, stream>>>(srcs, dsts, cursor, csr_src,
                                                    el, er, atten0_out, E);
    aggregate0<<<agg_blocks, 256, 0, stream>>>(row_off, csr_src, el, er,
                                               feat16, h1_16, N);

    // ---- layer 1 ----
    gemm_mfma1<<<gemm_blocks, 256, 0, stream>>>(h1_16, wth1, wtl1, feat16, al1, ar1,
                                                el, er, N, 128);
    layer1_fused<<<agg_blocks + edge_blocks, 256, 0, stream>>>(
        row_off, csr_src, el, er, feat16, h1_16, out, heads,
        srcs, dsts, e1_out, atten1_out, agg_blocks, N, E);
}

// Round 7
// 406.113 us; speedup vs baseline: 1.6255x; 1.0249x over previous
//
#include <hip/hip_runtime.h>
#include <hip/hip_bf16.h>

// GAT 2-layer forward for MI355X (gfx950). Round 10:
// - gemm0: fp16 split reduced to 2 passes (Xh@Wh + Xh@Wl); the dropped Xl@Wh
//   term is ~8e-4 (40x below current absmax). Frag read is now cvt-only.
//   gemm0 becomes X-read-bound (~17us floor).
// - aggregate: 2 nodes per wave (lane>=32 half handles the odd node);
//   per-wave serial chain (row_off->csr_src->shfl->gather) amortized over
//   2 nodes, wave count halved. Reduce = one shfl_xor(16); 4 cols/lane.
// 7 launches + 1 memset.
//
// d_out (floats): temp[N*128] | heads[4][N*32] | e1[E*4] | atten0[E] | atten1[E]
// Workspace: feat16(N*128 f16) | h1_16(N*128 f16) | el(N*4) | er(N*4) |
//            wth0/wtl0/wth1/wtl1 | ints: deg(N) row_off(N+1) cursor(N)
//            csr_src(E) bsums(256)

typedef _Float16 f16;
typedef _Float16 f16x2 __attribute__((ext_vector_type(2)));
typedef _Float16 f16x4 __attribute__((ext_vector_type(4)));
typedef _Float16 f16x8 __attribute__((ext_vector_type(8)));
typedef float f32x2 __attribute__((ext_vector_type(2)));
typedef float f32x4 __attribute__((ext_vector_type(4)));

__device__ __forceinline__ void gload16(const void* g, void* l) {
    __builtin_amdgcn_global_load_lds(
        (const __attribute__((address_space(1))) unsigned int*)g,
        (__attribute__((address_space(3))) unsigned int*)l, 16, 0, 0);
}

// ---- prep: W0/W1 split to [128][K] f16 hi/lo + degree count (fused) --------
__global__ void prep(const float* __restrict__ W0, const float* __restrict__ W1,
                     f16* __restrict__ Wth0, f16* __restrict__ Wtl0,
                     f16* __restrict__ Wth1, f16* __restrict__ Wtl1,
                     const int* __restrict__ dsts, int* __restrict__ deg, int E) {
    int i = blockIdx.x * blockDim.x + threadIdx.x;
    if (i < 256 * 128) {
        int k = i >> 7, c = i & 127;
        float v = W0[i];
        f16 h = (f16)v;
        Wth0[(size_t)c * 256 + k] = h;
        Wtl0[(size_t)c * 256 + k] = (f16)(v - (float)h);
    } else if (i < 256 * 128 + 128 * 128) {
        int j = i - 256 * 128;
        int k = j >> 7, c = j & 127;
        float v = W1[j];
        f16 h = (f16)v;
        Wth1[(size_t)c * 128 + k] = h;
        Wtl1[(size_t)c * 128 + k] = (f16)(v - (float)h);
    } else {
        int e = i - (256 * 128 + 128 * 128);
        if (e < E) atomicAdd(&deg[dsts[e]], 1);
    }
}

// ---------------- GEMM body: Y16 = fp16(X @ W), fused el/er epilogue ---------
// AFP16=0: X f32 staged direct-to-LDS [128][32] f32, granule XOR swizzle
//          (slot = g ^ (row&7)); cvt-to-f16 at frag read.
// AFP16=1: X f16 staged direct [128][32].
// Both: 2 MFMA passes (Ah@Wh + Ah@Wl).
// B staged [128][32] f16 linear; LDS row r holds phys col p=((r&15)<<3)|(r>>4),
// so lane lr owns phys cols lr*8..lr*8+7 -> packed f16x8 store + el/er via
// 16 fma + shfl_xor(1,2).
template <int AFP16>
__device__ __forceinline__ void gemm_body(
        int bid, const void* __restrict__ Xv, const f16* __restrict__ Wth,
        const f16* __restrict__ Wtl, f16* __restrict__ Y16,
        const float* __restrict__ al, const float* __restrict__ ar,
        float* __restrict__ el_out, float* __restrict__ er_out,
        int nrows, int K) {
    __shared__ float As32[AFP16 ? 1 : 128 * 32];  // 16 KB (L0 only)
    __shared__ f16   As16[AFP16 ? 128 * 32 : 1];  // 8 KB (L1 only)
    __shared__ f16   Bh[128 * 32];                // 8 KB
    __shared__ f16   Bl[128 * 32];                // 8 KB
    const int t    = threadIdx.x;
    const int wave = t >> 6;
    const int lane = t & 63;
    const int lr   = lane & 15;   // frag row (A) / col (B,D)
    const int kg   = lane >> 4;   // k-group 0..3
    const int row0 = bid * 128;

    f32x4 acc[2][8];
    #pragma unroll
    for (int i = 0; i < 2; ++i)
        #pragma unroll
        for (int j = 0; j < 8; ++j) acc[i][j] = (f32x4){0.f, 0.f, 0.f, 0.f};

    for (int k0 = 0; k0 < K; k0 += 32) {
        // ---- stage A (direct to LDS) ----
        if constexpr (!AFP16) {
            #pragma unroll
            for (int j = 0; j < 4; ++j) {
                int G = t + 256 * j;
                int row = G >> 3, slot = G & 7;
                int g = slot ^ (row & 7);
                int grow = row0 + row; if (grow >= nrows) grow = nrows - 1;
                gload16((const float*)Xv + (size_t)grow * K + k0 + g * 4,
                        &As32[G * 4]);
            }
        } else {
            #pragma unroll
            for (int j = 0; j < 2; ++j) {
                int G = t + 256 * j;
                int row = G >> 2, g4 = G & 3;
                int grow = row0 + row; if (grow >= nrows) grow = nrows - 1;
                gload16((const f16*)Xv + (size_t)grow * K + k0 + g4 * 8,
                        &As16[G * 8]);
            }
        }
        // ---- stage B hi/lo (direct, permuted source) ----
        #pragma unroll
        for (int j = 0; j < 2; ++j) {
            int G = t + 256 * j;
            int r = G >> 2, g4 = G & 3;
            int p = ((r & 15) << 3) | (r >> 4);
            gload16(Wth + (size_t)p * K + k0 + g4 * 8, &Bh[G * 8]);
            gload16(Wtl + (size_t)p * K + k0 + g4 * 8, &Bl[G * 8]);
        }
        __syncthreads();   // compiler drains vmcnt before barrier

        // ---- fragments ----
        const int ar0_ = wave * 32 + lr;
        f16x8 ah0, ah1;
        if constexpr (!AFP16) {
            int s0 = (2 * kg) ^ (lr & 7);
            int s1 = (2 * kg + 1) ^ (lr & 7);
            f32x4 u0 = *(const f32x4*)&As32[ar0_ * 32 + s0 * 4];
            f32x4 u1 = *(const f32x4*)&As32[ar0_ * 32 + s1 * 4];
            f32x4 v0 = *(const f32x4*)&As32[(ar0_ + 16) * 32 + s0 * 4];
            f32x4 v1 = *(const f32x4*)&As32[(ar0_ + 16) * 32 + s1 * 4];
            float a8[8] = {u0[0], u0[1], u0[2], u0[3], u1[0], u1[1], u1[2], u1[3]};
            float b8[8] = {v0[0], v0[1], v0[2], v0[3], v1[0], v1[1], v1[2], v1[3]};
            #pragma unroll
            for (int i = 0; i < 8; ++i) {
                ah0[i] = (f16)a8[i];
                ah1[i] = (f16)b8[i];
            }
        } else {
            ah0 = *(const f16x8*)&As16[ar0_ * 32 + kg * 8];
            ah1 = *(const f16x8*)&As16[(ar0_ + 16) * 32 + kg * 8];
        }
        f16x8 bh[8];
        #pragma unroll
        for (int cb = 0; cb < 8; ++cb)
            bh[cb] = *(const f16x8*)&Bh[(cb * 16 + lr) * 32 + kg * 8];

        // pass 1: Ah @ Wh
        #pragma unroll
        for (int cb = 0; cb < 8; ++cb) {
            acc[0][cb] = __builtin_amdgcn_mfma_f32_16x16x32_f16(ah0, bh[cb], acc[0][cb], 0, 0, 0);
            acc[1][cb] = __builtin_amdgcn_mfma_f32_16x16x32_f16(ah1, bh[cb], acc[1][cb], 0, 0, 0);
        }
        // pass 2: Ah @ Wl (Wl streamed)
        #pragma unroll
        for (int cb = 0; cb < 8; ++cb) {
            f16x8 bl = *(const f16x8*)&Bl[(cb * 16 + lr) * 32 + kg * 8];
            acc[0][cb] = __builtin_amdgcn_mfma_f32_16x16x32_f16(ah0, bl, acc[0][cb], 0, 0, 0);
            acc[1][cb] = __builtin_amdgcn_mfma_f32_16x16x32_f16(ah1, bl, acc[1][cb], 0, 0, 0);
        }
        __syncthreads();
    }

    // ---- epilogue: store f16 row chunks + fused el/er ----
    const int hh = lr >> 2;
    const int co = (lr & 3) * 8;
    float alv[8], arv[8];
    #pragma unroll
    for (int j = 0; j < 8; ++j) {
        alv[j] = al[hh * 32 + co + j];
        arv[j] = ar[hh * 32 + co + j];
    }
    #pragma unroll
    for (int rb = 0; rb < 2; ++rb) {
        int rbase = row0 + wave * 32 + rb * 16 + kg * 4;
        #pragma unroll
        for (int r = 0; r < 4; ++r) {
            int grow = rbase + r;
            f16x8 hv;
            float sl_ = 0.0f, sr_ = 0.0f;
            #pragma unroll
            for (int cb = 0; cb < 8; ++cb) {
                float v = acc[rb][cb][r];
                hv[cb] = (f16)v;
                sl_ += v * alv[cb];
                sr_ += v * arv[cb];
            }
            sl_ += __shfl_xor(sl_, 1); sl_ += __shfl_xor(sl_, 2);
            sr_ += __shfl_xor(sr_, 1); sr_ += __shfl_xor(sr_, 2);
            if (grow < nrows) {
                *(f16x8*)(Y16 + (size_t)grow * 128 + lr * 8) = hv;
                if ((lane & 3) == 0) {
                    el_out[4 * (size_t)grow + hh] = sl_;
                    er_out[4 * (size_t)grow + hh] = sr_;
                }
            }
        }
    }
}

// ---------------- CSR block scan body ----------------
__device__ __forceinline__ void scan_body(int b, const int* __restrict__ deg,
                                          int* __restrict__ excl,
                                          int* __restrict__ bsums, int n) {
    __shared__ int wsums[4];
    int t = threadIdx.x;
    int base = b * 1024;
    int idx = base + t * 4;
    int v[4];
    #pragma unroll
    for (int i = 0; i < 4; ++i) v[i] = (idx + i < n) ? deg[idx + i] : 0;
    int tsum = v[0] + v[1] + v[2] + v[3];
    int lane = t & 63, wid = t >> 6;
    int incl = tsum;
    #pragma unroll
    for (int off = 1; off < 64; off <<= 1) {
        int u = __shfl_up(incl, off, 64);
        if (lane >= off) incl += u;
    }
    if (lane == 63) wsums[wid] = incl;
    __syncthreads();
    if (t == 0) {
        int s = 0;
        #pragma unroll
        for (int w = 0; w < 4; ++w) { int x = wsums[w]; wsums[w] = s; s += x; }
    }
    __syncthreads();
    int ex = incl - tsum + wsums[wid];
    int run = ex;
    #pragma unroll
    for (int i = 0; i < 4; ++i) { if (idx + i < n) excl[idx + i] = run; run += v[i]; }
    if (t == 255) bsums[b] = ex + tsum;
}

// gemm layer-0 + CSR block-scan in one launch
__global__ __launch_bounds__(256, 2) void gemm0_scan(
        const float* __restrict__ X, const f16* __restrict__ Wth,
        const f16* __restrict__ Wtl, f16* __restrict__ Y16,
        const float* __restrict__ al, const float* __restrict__ ar,
        float* __restrict__ el_out, float* __restrict__ er_out,
        int nrows, int K, int gblocks,
        const int* __restrict__ deg, int* __restrict__ excl,
        int* __restrict__ bsums, int n) {
    if ((int)blockIdx.x < gblocks)
        gemm_body<0>(blockIdx.x, X, Wth, Wtl, Y16, al, ar, el_out, er_out, nrows, K);
    else
        scan_body(blockIdx.x - gblocks, deg, excl, bsums, n);
}

__global__ __launch_bounds__(256, 2) void gemm_mfma1(
        const f16* __restrict__ X, const f16* __restrict__ Wth,
        const f16* __restrict__ Wtl, f16* __restrict__ Y16,
        const float* __restrict__ al, const float* __restrict__ ar,
        float* __restrict__ el_out, float* __restrict__ er_out,
        int nrows, int K) {
    gemm_body<1>(blockIdx.x, X, Wth, Wtl, Y16, al, ar, el_out, er_out, nrows, K);
}

// fused scan_sums + finalize; also writes row_off[n] = E sentinel.
__global__ __launch_bounds__(256) void scan_fin(int* __restrict__ row_off,
                                                const int* __restrict__ bsums,
                                                int* __restrict__ cursor,
                                                const int* __restrict__ deg,
                                                int n, int nb) {
    __shared__ int spfx;
    int b = blockIdx.x;
    int t = threadIdx.x;
    if (t < 64) {
        int v = 0;
        if (t < b && t < nb) v = bsums[t];
        int t2 = t + 64;
        if (t2 < b && t2 < nb) v += bsums[t2];
        #pragma unroll
        for (int off = 32; off; off >>= 1) v += __shfl_xor(v, off, 64);
        if (t == 0) spfx = v;
    }
    __syncthreads();
    int pfx = spfx;
    int base = b * 1024 + t * 4;
    #pragma unroll
    for (int i2 = 0; i2 < 4; ++i2) {
        int i = base + i2;
        if (i < n) {
            int v = row_off[i] + pfx;
            row_off[i] = v;
            cursor[i]  = v;
            if (i == n - 1) row_off[n] = v + deg[i];
        }
    }
}

// ---------------- fused: CSR fill + layer-0 edge scores (atten0) ------------
__global__ void fill_csr_edge0(const int* __restrict__ srcs, const int* __restrict__ dsts,
                               int* __restrict__ cursor, int* __restrict__ csr_src,
                               const float* __restrict__ el, const float* __restrict__ er,
                               float* __restrict__ atten0, int E) {
    int e = blockIdx.x * blockDim.x + threadIdx.x;
    if (e >= E) return;
    int s = srcs[e], d = dsts[e];
    int p = atomicAdd(&cursor[d], 1);
    csr_src[p] = s;
    float4 elv = *(const float4*)(el + 4 * (size_t)s);
    float4 erv = *(const float4*)(er + 4 * (size_t)d);
    float v0 = elv.x + erv.x, v1 = elv.y + erv.y;
    float v2 = elv.z + erv.z, v3 = elv.w + erv.w;
    v0 = v0 > 0.0f ? v0 : 0.2f * v0;
    v1 = v1 > 0.0f ? v1 : 0.2f * v1;
    v2 = v2 > 0.0f ? v2 : 0.2f * v2;
    v3 = v3 > 0.0f ? v3 : 0.2f * v3;
    __builtin_nontemporal_store((v0 + v1 + v2 + v3) * 0.25f, atten0 + e);
}

// ---------------- layer-1 edge pass body ----------------
__device__ __forceinline__ void edge1_body(int bid,
        const int* __restrict__ srcs, const int* __restrict__ dsts,
        const float* __restrict__ el, const float* __restrict__ er,
        float* __restrict__ e1_out, float* __restrict__ atten1, int E) {
    int e = bid * 256 + threadIdx.x;
    if (e >= E) return;
    int s = srcs[e], d = dsts[e];
    float4 elv = *(const float4*)(el + 4 * (size_t)s);
    float4 erv = *(const float4*)(er + 4 * (size_t)d);
    float v0 = elv.x + erv.x, v1 = elv.y + erv.y;
    float v2 = elv.z + erv.z, v3 = elv.w + erv.w;
    v0 = v0 > 0.0f ? v0 : 0.2f * v0;
    v1 = v1 > 0.0f ? v1 : 0.2f * v1;
    v2 = v2 > 0.0f ? v2 : 0.2f * v2;
    v3 = v3 > 0.0f ? v3 : 0.2f * v3;
    __builtin_nontemporal_store((f32x4){v0, v1, v2, v3},
                                (f32x4*)(e1_out + 4 * (size_t)e));
    __builtin_nontemporal_store((v0 + v1 + v2 + v3) * 0.25f, atten1 + e);
}

// ---------------- gather aggregation body: one wave per TWO dst nodes -------
// half = lane>>5 selects the node; within a half: q2 = (lane>>4)&1 edge phase,
// sc = lane&15 col slot (cols sc*8..sc*8+7, head h = sc>>2). Each lane loads a
// contiguous f16x8 (16B); 16 lanes cover a row. w = exp(leaky(el[s]+er[d]))
// inline. Reduce = shfl_xor(16) (combines q2 phases, stays in-half); each lane
// writes 4 cols c0 = sc*8 + q2*4.
template <int LAYER>
__device__ __forceinline__ void agg_body(int bid,
        const int* __restrict__ row_off, const int* __restrict__ csr_src,
        const float* __restrict__ el, const float* __restrict__ er,
        const f16* __restrict__ feat16, const f16* __restrict__ resid16,
        f16* __restrict__ out16, float* __restrict__ out32,
        float* __restrict__ heads, int N) {
    int wv   = (bid * 256 + (int)threadIdx.x) >> 6;
    int lane = threadIdx.x & 63;
    int half = lane >> 5;
    int node = wv * 2 + half;
    int l31  = lane & 31;
    int q2 = (lane >> 4) & 1;    // edge phase 0..1
    int sc = lane & 15;          // col slot
    int h  = sc >> 2;            // head
    bool valid = node < N;
    int nclamp = valid ? node : N - 1;
    int start = row_off[nclamp];
    int dc    = valid ? (row_off[nclamp + 1] - start) : 0;
    float er_h = er[4 * (size_t)nclamp + h];

    float acc[8];
    #pragma unroll
    for (int j = 0; j < 8; ++j) acc[j] = 0.0f;
    float dh = 0.0f;
    const int base = half << 5;

    for (int cs = 0; cs < dc; cs += 32) {
        int act = dc - cs; if (act > 32) act = 32;
        int sl = (l31 < act) ? csr_src[start + cs + l31] : 0;
        int i = 0;
        for (; i + 4 <= act; i += 4) {
            int s0 = __shfl(sl, base + i + q2);
            int s1 = __shfl(sl, base + i + 2 + q2);
            float x0 = el[4 * (size_t)s0 + h] + er_h;
            float x1 = el[4 * (size_t)s1 + h] + er_h;
            x0 = x0 > 0.0f ? x0 : 0.2f * x0;
            x1 = x1 > 0.0f ? x1 : 0.2f * x1;
            float w0 = __expf(x0);
            float w1 = __expf(x1);
            f16x8 f0 = *(const f16x8*)(feat16 + 128 * (size_t)s0 + sc * 8);
            f16x8 f1 = *(const f16x8*)(feat16 + 128 * (size_t)s1 + sc * 8);
            #pragma unroll
            for (int j = 0; j < 8; ++j) acc[j] += w0 * (float)f0[j];
            #pragma unroll
            for (int j = 0; j < 8; ++j) acc[j] += w1 * (float)f1[j];
            dh += w0 + w1;
        }
        for (; i < act; i += 2) {
            int e = i + q2;
            bool on = e < act;
            int s = __shfl(sl, base + (on ? e : 0));
            float x = el[4 * (size_t)s + h] + er_h;
            x = x > 0.0f ? x : 0.2f * x;
            float w = on ? __expf(x) : 0.0f;
            f16x8 fv = *(const f16x8*)(feat16 + 128 * (size_t)s + sc * 8);
            #pragma unroll
            for (int j = 0; j < 8; ++j) acc[j] += w * (float)fv[j];
            dh += w;
        }
    }

    // combine the 2 q2-phases (xor16 flips bit4 only -> stays within half)
    #pragma unroll
    for (int j = 0; j < 8; ++j) acc[j] += __shfl_xor(acc[j], 16);
    dh += __shfl_xor(dh, 16);
    if (!valid) return;

    float inv = (dc > 0) ? 1.0f / dh : 0.0f;
    // lane writes cols c0 = sc*8 + q2*4 .. +3 (static select)
    float r0 = (q2 ? acc[4] : acc[0]) * inv;
    float r1 = (q2 ? acc[5] : acc[1]) * inv;
    float r2 = (q2 ? acc[6] : acc[2]) * inv;
    float r3 = (q2 ? acc[7] : acc[3]) * inv;
    int c0 = sc * 8 + q2 * 4;
    size_t o = 128 * (size_t)node + c0;
    if (LAYER == 1) {
        f16x4 rv = *(const f16x4*)(resid16 + o);
        r0 += (float)rv[0]; r1 += (float)rv[1];
        r2 += (float)rv[2]; r3 += (float)rv[3];
    }
    r0 = r0 > 0.0f ? r0 : __expf(r0) - 1.0f;
    r1 = r1 > 0.0f ? r1 : __expf(r1) - 1.0f;
    r2 = r2 > 0.0f ? r2 : __expf(r2) - 1.0f;
    r3 = r3 > 0.0f ? r3 : __expf(r3) - 1.0f;
    if (LAYER == 0) {
        f16x4 hv; hv[0] = (f16)r0; hv[1] = (f16)r1; hv[2] = (f16)r2; hv[3] = (f16)r3;
        *(f16x4*)(out16 + o) = hv;
    } else {
        __builtin_nontemporal_store((f32x4){r0, r1, r2, r3}, (f32x4*)(out32 + o));
        __builtin_nontemporal_store(
            (f32x4){r0, r1, r2, r3},
            (f32x4*)(heads + (size_t)h * N * 32 + (size_t)node * 32 + (c0 & 31)));
    }
}

__global__ __launch_bounds__(256) void aggregate0(const int* __restrict__ row_off,
                                                  const int* __restrict__ csr_src,
                                                  const float* __restrict__ el,
                                                  const float* __restrict__ er,
                                                  const f16* __restrict__ feat16,
                                                  f16* __restrict__ out16, int N) {
    agg_body<0>(blockIdx.x, row_off, csr_src, el, er, feat16, nullptr,
                out16, nullptr, nullptr, N);
}

// aggregate<1> + edge1 in one launch (both gated only by gemm1; independent)
__global__ __launch_bounds__(256) void layer1_fused(
        const int* __restrict__ row_off, const int* __restrict__ csr_src,
        const float* __restrict__ el, const float* __restrict__ er,
        const f16* __restrict__ feat16, const f16* __restrict__ resid16,
        float* __restrict__ out32, float* __restrict__ heads,
        const int* __restrict__ srcs, const int* __restrict__ dsts,
        float* __restrict__ e1_out, float* __restrict__ atten1,
        int aggBlocks, int N, int E) {
    if ((int)blockIdx.x < aggBlocks)
        agg_body<1>(blockIdx.x, row_off, csr_src, el, er, feat16, resid16,
                    nullptr, out32, heads, N);
    else
        edge1_body(blockIdx.x - aggBlocks, srcs, dsts, el, er, e1_out, atten1, E);
}

extern "C" void kernel_launch(void* const* d_in, const int* in_sizes, int n_in,
                              void* d_out, int out_size, void* d_ws, size_t ws_size,
                              hipStream_t stream) {
    const float* x   = (const float*)d_in[0];
    const int*   ei  = (const int*)d_in[1];
    const float* W0  = (const float*)d_in[2];
    const float* al0 = (const float*)d_in[3];
    const float* ar0 = (const float*)d_in[4];
    const float* W1  = (const float*)d_in[5];
    const float* al1 = (const float*)d_in[6];
    const float* ar1 = (const float*)d_in[7];

    const int N = in_sizes[0] / 256;     // 100000
    const int E = in_sizes[1] / 2;       // 800000
    const size_t NF = (size_t)N * 128;

    const int* srcs = ei;
    const int* dsts = ei + E;

    float* out = (float*)d_out;
    f16*   f16ws  = (f16*)d_ws;
    f16*   feat16 = f16ws;                               // N*128 f16
    f16*   h1_16  = feat16 + NF;                         // N*128 f16
    float* el   = (float*)(h1_16 + NF);                  // N*4
    float* er   = el + (size_t)N * 4;                    // N*4
    f16*   wth0 = (f16*)(er + (size_t)N * 4);            // 128*256
    f16*   wtl0 = wth0 + (size_t)128 * 256;              // 128*256
    f16*   wth1 = wtl0 + (size_t)128 * 256;              // 128*128
    f16*   wtl1 = wth1 + (size_t)128 * 128;              // 128*128
    int*   ints    = (int*)(wtl1 + (size_t)128 * 128);
    int*   deg     = ints;                               // N
    int*   row_off = deg + N;                            // N+1 (sentinel)
    int*   cursor  = row_off + N + 1;                    // N
    int*   csr_src = cursor + N;                         // E
    int*   bsums   = csr_src + E;                        // <=256

    float* heads      = out + NF;
    float* e1_out     = out + 2 * NF;
    float* atten0_out = e1_out + (size_t)E * 4;
    float* atten1_out = atten0_out + E;

    // ---- prep: weight split + degree count (one launch) ----
    hipMemsetAsync(deg, 0, (size_t)N * sizeof(int), stream);
    const int wtot = 256 * 128 + 128 * 128;
    prep<<<(wtot + E + 255) / 256, 256, 0, stream>>>(W0, W1, wth0, wtl0, wth1, wtl1,
                                                     dsts, deg, E);

    const int gemm_blocks = (N + 127) / 128;
    const int agg_blocks  = (N + 7) / 8;      // 2 nodes/wave, 4 waves/block
    const int edge_blocks = (E + 255) / 256;
    const int nb = (N + 1023) / 1024;

    // ---- layer 0: gemm + CSR block-scan in one launch ----
    gemm0_scan<<<gemm_blocks + nb, 256, 0, stream>>>(x, wth0, wtl0, feat16, al0, ar0,
                                                     el, er, N, 256, gemm_blocks,
                                                     deg, row_off, bsums, N);
    scan_fin<<<nb, 256, 0, stream>>>(row_off, bsums, cursor, deg, N, nb);
    fill_csr_edge0<<<edge_blocks, 256, 0, stream>>>(srcs, dsts, cursor, csr_src,
                                                    el, er, atten0_out, E);
    aggregate0<<<agg_blocks, 256, 0, stream>>>(row_off, csr_src, el, er,
                                               feat16, h1_16, N);

    // ---- layer 1 ----
    gemm_mfma1<<<gemm_blocks, 256, 0, stream>>>(h1_16, wth1, wtl1, feat16, al1, ar1,
                                                el, er, N, 128);
    layer1_fused<<<agg_blocks + edge_blocks, 256, 0, stream>>>(
        row_off, csr_src, el, er, feat16, h1_16, out, heads,
        srcs, dsts, e1_out, atten1_out, agg_blocks, N, E);
}

// Round 8
// 401.844 us; speedup vs baseline: 1.6428x; 1.0106x over previous
//
#include <hip/hip_runtime.h>
#include <hip/hip_bf16.h>

// GAT 2-layer forward for MI355X (gfx950). Round 11:
// - gemm1: single MFMA pass (Ah@Wh); dropped W1-lo term ~5e-4 (15x under
//   absmax). Bl staging skipped for layer 1.
// - aggregate: 8-edge unrolled inner body (4 gathers in flight per lane) to
//   cover the typical deg-8 node in one issue burst.
// - __launch_bounds__(256,4) on GEMMs (est ~100 VGPR < 128, spill-free).
// 7 launches + 1 memset.
//
// d_out (floats): temp[N*128] | heads[4][N*32] | e1[E*4] | atten0[E] | atten1[E]
// Workspace: feat16(N*128 f16) | h1_16(N*128 f16) | el(N*4) | er(N*4) |
//            wth0/wtl0/wth1/wtl1 | ints: deg(N) row_off(N+1) cursor(N)
//            csr_src(E) bsums(256)

typedef _Float16 f16;
typedef _Float16 f16x2 __attribute__((ext_vector_type(2)));
typedef _Float16 f16x4 __attribute__((ext_vector_type(4)));
typedef _Float16 f16x8 __attribute__((ext_vector_type(8)));
typedef float f32x2 __attribute__((ext_vector_type(2)));
typedef float f32x4 __attribute__((ext_vector_type(4)));

__device__ __forceinline__ void gload16(const void* g, void* l) {
    __builtin_amdgcn_global_load_lds(
        (const __attribute__((address_space(1))) unsigned int*)g,
        (__attribute__((address_space(3))) unsigned int*)l, 16, 0, 0);
}

// ---- prep: W0/W1 split to [128][K] f16 hi/lo + degree count (fused) --------
__global__ void prep(const float* __restrict__ W0, const float* __restrict__ W1,
                     f16* __restrict__ Wth0, f16* __restrict__ Wtl0,
                     f16* __restrict__ Wth1,
                     const int* __restrict__ dsts, int* __restrict__ deg, int E) {
    int i = blockIdx.x * blockDim.x + threadIdx.x;
    if (i < 256 * 128) {
        int k = i >> 7, c = i & 127;
        float v = W0[i];
        f16 h = (f16)v;
        Wth0[(size_t)c * 256 + k] = h;
        Wtl0[(size_t)c * 256 + k] = (f16)(v - (float)h);
    } else if (i < 256 * 128 + 128 * 128) {
        int j = i - 256 * 128;
        int k = j >> 7, c = j & 127;
        Wth1[(size_t)c * 128 + k] = (f16)W1[j];
    } else {
        int e = i - (256 * 128 + 128 * 128);
        if (e < E) atomicAdd(&deg[dsts[e]], 1);
    }
}

// ---------------- GEMM body: Y16 = fp16(X @ W), fused el/er epilogue ---------
// AFP16=0: X f32 staged direct-to-LDS [128][32] f32, granule XOR swizzle
//          (slot = g ^ (row&7)); cvt-to-f16 at frag read; 2 passes (Wh + Wl).
// AFP16=1: X f16 staged direct [128][32]; 1 pass (Wh only).
// B staged [128][32] f16 linear; LDS row r holds phys col p=((r&15)<<3)|(r>>4),
// so lane lr owns phys cols lr*8..lr*8+7 -> packed f16x8 store + el/er via
// 16 fma + shfl_xor(1,2).
template <int AFP16>
__device__ __forceinline__ void gemm_body(
        int bid, const void* __restrict__ Xv, const f16* __restrict__ Wth,
        const f16* __restrict__ Wtl, f16* __restrict__ Y16,
        const float* __restrict__ al, const float* __restrict__ ar,
        float* __restrict__ el_out, float* __restrict__ er_out,
        int nrows, int K) {
    __shared__ float As32[AFP16 ? 1 : 128 * 32];  // 16 KB (L0 only)
    __shared__ f16   As16[AFP16 ? 128 * 32 : 1];  // 8 KB (L1 only)
    __shared__ f16   Bh[128 * 32];                // 8 KB
    __shared__ f16   Bl[AFP16 ? 1 : 128 * 32];    // 8 KB (L0 only)
    const int t    = threadIdx.x;
    const int wave = t >> 6;
    const int lane = t & 63;
    const int lr   = lane & 15;   // frag row (A) / col (B,D)
    const int kg   = lane >> 4;   // k-group 0..3
    const int row0 = bid * 128;

    f32x4 acc[2][8];
    #pragma unroll
    for (int i = 0; i < 2; ++i)
        #pragma unroll
        for (int j = 0; j < 8; ++j) acc[i][j] = (f32x4){0.f, 0.f, 0.f, 0.f};

    for (int k0 = 0; k0 < K; k0 += 32) {
        // ---- stage A (direct to LDS) ----
        if constexpr (!AFP16) {
            #pragma unroll
            for (int j = 0; j < 4; ++j) {
                int G = t + 256 * j;
                int row = G >> 3, slot = G & 7;
                int g = slot ^ (row & 7);
                int grow = row0 + row; if (grow >= nrows) grow = nrows - 1;
                gload16((const float*)Xv + (size_t)grow * K + k0 + g * 4,
                        &As32[G * 4]);
            }
        } else {
            #pragma unroll
            for (int j = 0; j < 2; ++j) {
                int G = t + 256 * j;
                int row = G >> 2, g4 = G & 3;
                int grow = row0 + row; if (grow >= nrows) grow = nrows - 1;
                gload16((const f16*)Xv + (size_t)grow * K + k0 + g4 * 8,
                        &As16[G * 8]);
            }
        }
        // ---- stage B (direct, permuted source) ----
        #pragma unroll
        for (int j = 0; j < 2; ++j) {
            int G = t + 256 * j;
            int r = G >> 2, g4 = G & 3;
            int p = ((r & 15) << 3) | (r >> 4);
            gload16(Wth + (size_t)p * K + k0 + g4 * 8, &Bh[G * 8]);
            if constexpr (!AFP16)
                gload16(Wtl + (size_t)p * K + k0 + g4 * 8, &Bl[G * 8]);
        }
        __syncthreads();   // compiler drains vmcnt before barrier

        // ---- fragments ----
        const int ar0_ = wave * 32 + lr;
        f16x8 ah0, ah1;
        if constexpr (!AFP16) {
            int s0 = (2 * kg) ^ (lr & 7);
            int s1 = (2 * kg + 1) ^ (lr & 7);
            f32x4 u0 = *(const f32x4*)&As32[ar0_ * 32 + s0 * 4];
            f32x4 u1 = *(const f32x4*)&As32[ar0_ * 32 + s1 * 4];
            f32x4 v0 = *(const f32x4*)&As32[(ar0_ + 16) * 32 + s0 * 4];
            f32x4 v1 = *(const f32x4*)&As32[(ar0_ + 16) * 32 + s1 * 4];
            float a8[8] = {u0[0], u0[1], u0[2], u0[3], u1[0], u1[1], u1[2], u1[3]};
            float b8[8] = {v0[0], v0[1], v0[2], v0[3], v1[0], v1[1], v1[2], v1[3]};
            #pragma unroll
            for (int i = 0; i < 8; ++i) {
                ah0[i] = (f16)a8[i];
                ah1[i] = (f16)b8[i];
            }
        } else {
            ah0 = *(const f16x8*)&As16[ar0_ * 32 + kg * 8];
            ah1 = *(const f16x8*)&As16[(ar0_ + 16) * 32 + kg * 8];
        }
        f16x8 bh[8];
        #pragma unroll
        for (int cb = 0; cb < 8; ++cb)
            bh[cb] = *(const f16x8*)&Bh[(cb * 16 + lr) * 32 + kg * 8];

        // pass 1: Ah @ Wh
        #pragma unroll
        for (int cb = 0; cb < 8; ++cb) {
            acc[0][cb] = __builtin_amdgcn_mfma_f32_16x16x32_f16(ah0, bh[cb], acc[0][cb], 0, 0, 0);
            acc[1][cb] = __builtin_amdgcn_mfma_f32_16x16x32_f16(ah1, bh[cb], acc[1][cb], 0, 0, 0);
        }
        // pass 2: Ah @ Wl (layer 0 only; Wl streamed)
        if constexpr (!AFP16) {
            #pragma unroll
            for (int cb = 0; cb < 8; ++cb) {
                f16x8 bl = *(const f16x8*)&Bl[(cb * 16 + lr) * 32 + kg * 8];
                acc[0][cb] = __builtin_amdgcn_mfma_f32_16x16x32_f16(ah0, bl, acc[0][cb], 0, 0, 0);
                acc[1][cb] = __builtin_amdgcn_mfma_f32_16x16x32_f16(ah1, bl, acc[1][cb], 0, 0, 0);
            }
        }
        __syncthreads();
    }

    // ---- epilogue: store f16 row chunks + fused el/er ----
    const int hh = lr >> 2;
    const int co = (lr & 3) * 8;
    float alv[8], arv[8];
    #pragma unroll
    for (int j = 0; j < 8; ++j) {
        alv[j] = al[hh * 32 + co + j];
        arv[j] = ar[hh * 32 + co + j];
    }
    #pragma unroll
    for (int rb = 0; rb < 2; ++rb) {
        int rbase = row0 + wave * 32 + rb * 16 + kg * 4;
        #pragma unroll
        for (int r = 0; r < 4; ++r) {
            int grow = rbase + r;
            f16x8 hv;
            float sl_ = 0.0f, sr_ = 0.0f;
            #pragma unroll
            for (int cb = 0; cb < 8; ++cb) {
                float v = acc[rb][cb][r];
                hv[cb] = (f16)v;
                sl_ += v * alv[cb];
                sr_ += v * arv[cb];
            }
            sl_ += __shfl_xor(sl_, 1); sl_ += __shfl_xor(sl_, 2);
            sr_ += __shfl_xor(sr_, 1); sr_ += __shfl_xor(sr_, 2);
            if (grow < nrows) {
                *(f16x8*)(Y16 + (size_t)grow * 128 + lr * 8) = hv;
                if ((lane & 3) == 0) {
                    el_out[4 * (size_t)grow + hh] = sl_;
                    er_out[4 * (size_t)grow + hh] = sr_;
                }
            }
        }
    }
}

// ---------------- CSR block scan body ----------------
__device__ __forceinline__ void scan_body(int b, const int* __restrict__ deg,
                                          int* __restrict__ excl,
                                          int* __restrict__ bsums, int n) {
    __shared__ int wsums[4];
    int t = threadIdx.x;
    int base = b * 1024;
    int idx = base + t * 4;
    int v[4];
    #pragma unroll
    for (int i = 0; i < 4; ++i) v[i] = (idx + i < n) ? deg[idx + i] : 0;
    int tsum = v[0] + v[1] + v[2] + v[3];
    int lane = t & 63, wid = t >> 6;
    int incl = tsum;
    #pragma unroll
    for (int off = 1; off < 64; off <<= 1) {
        int u = __shfl_up(incl, off, 64);
        if (lane >= off) incl += u;
    }
    if (lane == 63) wsums[wid] = incl;
    __syncthreads();
    if (t == 0) {
        int s = 0;
        #pragma unroll
        for (int w = 0; w < 4; ++w) { int x = wsums[w]; wsums[w] = s; s += x; }
    }
    __syncthreads();
    int ex = incl - tsum + wsums[wid];
    int run = ex;
    #pragma unroll
    for (int i = 0; i < 4; ++i) { if (idx + i < n) excl[idx + i] = run; run += v[i]; }
    if (t == 255) bsums[b] = ex + tsum;
}

// gemm layer-0 + CSR block-scan in one launch
__global__ __launch_bounds__(256, 4) void gemm0_scan(
        const float* __restrict__ X, const f16* __restrict__ Wth,
        const f16* __restrict__ Wtl, f16* __restrict__ Y16,
        const float* __restrict__ al, const float* __restrict__ ar,
        float* __restrict__ el_out, float* __restrict__ er_out,
        int nrows, int K, int gblocks,
        const int* __restrict__ deg, int* __restrict__ excl,
        int* __restrict__ bsums, int n) {
    if ((int)blockIdx.x < gblocks)
        gemm_body<0>(blockIdx.x, X, Wth, Wtl, Y16, al, ar, el_out, er_out, nrows, K);
    else
        scan_body(blockIdx.x - gblocks, deg, excl, bsums, n);
}

__global__ __launch_bounds__(256, 4) void gemm_mfma1(
        const f16* __restrict__ X, const f16* __restrict__ Wth,
        f16* __restrict__ Y16,
        const float* __restrict__ al, const float* __restrict__ ar,
        float* __restrict__ el_out, float* __restrict__ er_out,
        int nrows, int K) {
    gemm_body<1>(blockIdx.x, X, Wth, nullptr, Y16, al, ar, el_out, er_out, nrows, K);
}

// fused scan_sums + finalize; also writes row_off[n] = E sentinel.
__global__ __launch_bounds__(256) void scan_fin(int* __restrict__ row_off,
                                                const int* __restrict__ bsums,
                                                int* __restrict__ cursor,
                                                const int* __restrict__ deg,
                                                int n, int nb) {
    __shared__ int spfx;
    int b = blockIdx.x;
    int t = threadIdx.x;
    if (t < 64) {
        int v = 0;
        if (t < b && t < nb) v = bsums[t];
        int t2 = t + 64;
        if (t2 < b && t2 < nb) v += bsums[t2];
        #pragma unroll
        for (int off = 32; off; off >>= 1) v += __shfl_xor(v, off, 64);
        if (t == 0) spfx = v;
    }
    __syncthreads();
    int pfx = spfx;
    int base = b * 1024 + t * 4;
    #pragma unroll
    for (int i2 = 0; i2 < 4; ++i2) {
        int i = base + i2;
        if (i < n) {
            int v = row_off[i] + pfx;
            row_off[i] = v;
            cursor[i]  = v;
            if (i == n - 1) row_off[n] = v + deg[i];
        }
    }
}

// ---------------- fused: CSR fill + layer-0 edge scores (atten0) ------------
__global__ void fill_csr_edge0(const int* __restrict__ srcs, const int* __restrict__ dsts,
                               int* __restrict__ cursor, int* __restrict__ csr_src,
                               const float* __restrict__ el, const float* __restrict__ er,
                               float* __restrict__ atten0, int E) {
    int e = blockIdx.x * blockDim.x + threadIdx.x;
    if (e >= E) return;
    int s = srcs[e], d = dsts[e];
    int p = atomicAdd(&cursor[d], 1);
    csr_src[p] = s;
    float4 elv = *(const float4*)(el + 4 * (size_t)s);
    float4 erv = *(const float4*)(er + 4 * (size_t)d);
    float v0 = elv.x + erv.x, v1 = elv.y + erv.y;
    float v2 = elv.z + erv.z, v3 = elv.w + erv.w;
    v0 = v0 > 0.0f ? v0 : 0.2f * v0;
    v1 = v1 > 0.0f ? v1 : 0.2f * v1;
    v2 = v2 > 0.0f ? v2 : 0.2f * v2;
    v3 = v3 > 0.0f ? v3 : 0.2f * v3;
    __builtin_nontemporal_store((v0 + v1 + v2 + v3) * 0.25f, atten0 + e);
}

// ---------------- layer-1 edge pass body ----------------
__device__ __forceinline__ void edge1_body(int bid,
        const int* __restrict__ srcs, const int* __restrict__ dsts,
        const float* __restrict__ el, const float* __restrict__ er,
        float* __restrict__ e1_out, float* __restrict__ atten1, int E) {
    int e = bid * 256 + threadIdx.x;
    if (e >= E) return;
    int s = srcs[e], d = dsts[e];
    float4 elv = *(const float4*)(el + 4 * (size_t)s);
    float4 erv = *(const float4*)(er + 4 * (size_t)d);
    float v0 = elv.x + erv.x, v1 = elv.y + erv.y;
    float v2 = elv.z + erv.z, v3 = elv.w + erv.w;
    v0 = v0 > 0.0f ? v0 : 0.2f * v0;
    v1 = v1 > 0.0f ? v1 : 0.2f * v1;
    v2 = v2 > 0.0f ? v2 : 0.2f * v2;
    v3 = v3 > 0.0f ? v3 : 0.2f * v3;
    __builtin_nontemporal_store((f32x4){v0, v1, v2, v3},
                                (f32x4*)(e1_out + 4 * (size_t)e));
    __builtin_nontemporal_store((v0 + v1 + v2 + v3) * 0.25f, atten1 + e);
}

// ---------------- gather aggregation body: one wave per TWO dst nodes -------
// half = lane>>5 selects the node; within a half: q2 = (lane>>4)&1 edge phase,
// sc = lane&15 col slot (cols sc*8..sc*8+7, head h = sc>>2). Each lane loads a
// contiguous f16x8 (16B); 16 lanes cover a row. w = exp(leaky(el[s]+er[d]))
// inline. Inner body unrolled 8 edges (4 gathers in flight/lane). Reduce =
// shfl_xor(16); each lane writes 4 cols c0 = sc*8 + q2*4.
template <int LAYER>
__device__ __forceinline__ void agg_body(int bid,
        const int* __restrict__ row_off, const int* __restrict__ csr_src,
        const float* __restrict__ el, const float* __restrict__ er,
        const f16* __restrict__ feat16, const f16* __restrict__ resid16,
        f16* __restrict__ out16, float* __restrict__ out32,
        float* __restrict__ heads, int N) {
    int wv   = (bid * 256 + (int)threadIdx.x) >> 6;
    int lane = threadIdx.x & 63;
    int half = lane >> 5;
    int node = wv * 2 + half;
    int l31  = lane & 31;
    int q2 = (lane >> 4) & 1;    // edge phase 0..1
    int sc = lane & 15;          // col slot
    int h  = sc >> 2;            // head
    bool valid = node < N;
    int nclamp = valid ? node : N - 1;
    int start = row_off[nclamp];
    int dc    = valid ? (row_off[nclamp + 1] - start) : 0;
    float er_h = er[4 * (size_t)nclamp + h];

    float acc[8];
    #pragma unroll
    for (int j = 0; j < 8; ++j) acc[j] = 0.0f;
    float dh = 0.0f;
    const int base = half << 5;

    for (int cs = 0; cs < dc; cs += 32) {
        int act = dc - cs; if (act > 32) act = 32;
        int sl = (l31 < act) ? csr_src[start + cs + l31] : 0;
        int i = 0;
        for (; i + 8 <= act; i += 8) {
            int s0 = __shfl(sl, base + i + q2);
            int s1 = __shfl(sl, base + i + 2 + q2);
            int s2 = __shfl(sl, base + i + 4 + q2);
            int s3 = __shfl(sl, base + i + 6 + q2);
            float x0 = el[4 * (size_t)s0 + h] + er_h;
            float x1 = el[4 * (size_t)s1 + h] + er_h;
            float x2 = el[4 * (size_t)s2 + h] + er_h;
            float x3 = el[4 * (size_t)s3 + h] + er_h;
            x0 = x0 > 0.0f ? x0 : 0.2f * x0;
            x1 = x1 > 0.0f ? x1 : 0.2f * x1;
            x2 = x2 > 0.0f ? x2 : 0.2f * x2;
            x3 = x3 > 0.0f ? x3 : 0.2f * x3;
            float w0 = __expf(x0);
            float w1 = __expf(x1);
            float w2 = __expf(x2);
            float w3 = __expf(x3);
            f16x8 f0 = *(const f16x8*)(feat16 + 128 * (size_t)s0 + sc * 8);
            f16x8 f1 = *(const f16x8*)(feat16 + 128 * (size_t)s1 + sc * 8);
            f16x8 f2 = *(const f16x8*)(feat16 + 128 * (size_t)s2 + sc * 8);
            f16x8 f3 = *(const f16x8*)(feat16 + 128 * (size_t)s3 + sc * 8);
            #pragma unroll
            for (int j = 0; j < 8; ++j) acc[j] += w0 * (float)f0[j];
            #pragma unroll
            for (int j = 0; j < 8; ++j) acc[j] += w1 * (float)f1[j];
            #pragma unroll
            for (int j = 0; j < 8; ++j) acc[j] += w2 * (float)f2[j];
            #pragma unroll
            for (int j = 0; j < 8; ++j) acc[j] += w3 * (float)f3[j];
            dh += w0 + w1 + w2 + w3;
        }
        for (; i + 4 <= act; i += 4) {
            int s0 = __shfl(sl, base + i + q2);
            int s1 = __shfl(sl, base + i + 2 + q2);
            float x0 = el[4 * (size_t)s0 + h] + er_h;
            float x1 = el[4 * (size_t)s1 + h] + er_h;
            x0 = x0 > 0.0f ? x0 : 0.2f * x0;
            x1 = x1 > 0.0f ? x1 : 0.2f * x1;
            float w0 = __expf(x0);
            float w1 = __expf(x1);
            f16x8 f0 = *(const f16x8*)(feat16 + 128 * (size_t)s0 + sc * 8);
            f16x8 f1 = *(const f16x8*)(feat16 + 128 * (size_t)s1 + sc * 8);
            #pragma unroll
            for (int j = 0; j < 8; ++j) acc[j] += w0 * (float)f0[j];
            #pragma unroll
            for (int j = 0; j < 8; ++j) acc[j] += w1 * (float)f1[j];
            dh += w0 + w1;
        }
        for (; i < act; i += 2) {
            int e = i + q2;
            bool on = e < act;
            int s = __shfl(sl, base + (on ? e : 0));
            float x = el[4 * (size_t)s + h] + er_h;
            x = x > 0.0f ? x : 0.2f * x;
            float w = on ? __expf(x) : 0.0f;
            f16x8 fv = *(const f16x8*)(feat16 + 128 * (size_t)s + sc * 8);
            #pragma unroll
            for (int j = 0; j < 8; ++j) acc[j] += w * (float)fv[j];
            dh += w;
        }
    }

    // combine the 2 q2-phases (xor16 flips bit4 only -> stays within half)
    #pragma unroll
    for (int j = 0; j < 8; ++j) acc[j] += __shfl_xor(acc[j], 16);
    dh += __shfl_xor(dh, 16);
    if (!valid) return;

    float inv = (dc > 0) ? 1.0f / dh : 0.0f;
    // lane writes cols c0 = sc*8 + q2*4 .. +3 (static select)
    float r0 = (q2 ? acc[4] : acc[0]) * inv;
    float r1 = (q2 ? acc[5] : acc[1]) * inv;
    float r2 = (q2 ? acc[6] : acc[2]) * inv;
    float r3 = (q2 ? acc[7] : acc[3]) * inv;
    int c0 = sc * 8 + q2 * 4;
    size_t o = 128 * (size_t)node + c0;
    if (LAYER == 1) {
        f16x4 rv = *(const f16x4*)(resid16 + o);
        r0 += (float)rv[0]; r1 += (float)rv[1];
        r2 += (float)rv[2]; r3 += (float)rv[3];
    }
    r0 = r0 > 0.0f ? r0 : __expf(r0) - 1.0f;
    r1 = r1 > 0.0f ? r1 : __expf(r1) - 1.0f;
    r2 = r2 > 0.0f ? r2 : __expf(r2) - 1.0f;
    r3 = r3 > 0.0f ? r3 : __expf(r3) - 1.0f;
    if (LAYER == 0) {
        f16x4 hv; hv[0] = (f16)r0; hv[1] = (f16)r1; hv[2] = (f16)r2; hv[3] = (f16)r3;
        *(f16x4*)(out16 + o) = hv;
    } else {
        __builtin_nontemporal_store((f32x4){r0, r1, r2, r3}, (f32x4*)(out32 + o));
        __builtin_nontemporal_store(
            (f32x4){r0, r1, r2, r3},
            (f32x4*)(heads + (size_t)h * N * 32 + (size_t)node * 32 + (c0 & 31)));
    }
}

__global__ __launch_bounds__(256) void aggregate0(const int* __restrict__ row_off,
                                                  const int* __restrict__ csr_src,
                                                  const float* __restrict__ el,
                                                  const float* __restrict__ er,
                                                  const f16* __restrict__ feat16,
                                                  f16* __restrict__ out16, int N) {
    agg_body<0>(blockIdx.x, row_off, csr_src, el, er, feat16, nullptr,
                out16, nullptr, nullptr, N);
}

// aggregate<1> + edge1 in one launch (both gated only by gemm1; independent)
__global__ __launch_bounds__(256) void layer1_fused(
        const int* __restrict__ row_off, const int* __restrict__ csr_src,
        const float* __restrict__ el, const float* __restrict__ er,
        const f16* __restrict__ feat16, const f16* __restrict__ resid16,
        float* __restrict__ out32, float* __restrict__ heads,
        const int* __restrict__ srcs, const int* __restrict__ dsts,
        float* __restrict__ e1_out, float* __restrict__ atten1,
        int aggBlocks, int N, int E) {
    if ((int)blockIdx.x < aggBlocks)
        agg_body<1>(blockIdx.x, row_off, csr_src, el, er, feat16, resid16,
                    nullptr, out32, heads, N);
    else
        edge1_body(blockIdx.x - aggBlocks, srcs, dsts, el, er, e1_out, atten1, E);
}

extern "C" void kernel_launch(void* const* d_in, const int* in_sizes, int n_in,
                              void* d_out, int out_size, void* d_ws, size_t ws_size,
                              hipStream_t stream) {
    const float* x   = (const float*)d_in[0];
    const int*   ei  = (const int*)d_in[1];
    const float* W0  = (const float*)d_in[2];
    const float* al0 = (const float*)d_in[3];
    const float* ar0 = (const float*)d_in[4];
    const float* W1  = (const float*)d_in[5];
    const float* al1 = (const float*)d_in[6];
    const float* ar1 = (const float*)d_in[7];

    const int N = in_sizes[0] / 256;     // 100000
    const int E = in_sizes[1] / 2;       // 800000
    const size_t NF = (size_t)N * 128;

    const int* srcs = ei;
    const int* dsts = ei + E;

    float* out = (float*)d_out;
    f16*   f16ws  = (f16*)d_ws;
    f16*   feat16 = f16ws;                               // N*128 f16
    f16*   h1_16  = feat16 + NF;                         // N*128 f16
    float* el   = (float*)(h1_16 + NF);                  // N*4
    float* er   = el + (size_t)N * 4;                    // N*4
    f16*   wth0 = (f16*)(er + (size_t)N * 4);            // 128*256
    f16*   wtl0 = wth0 + (size_t)128 * 256;              // 128*256
    f16*   wth1 = wtl0 + (size_t)128 * 256;              // 128*128
    int*   ints    = (int*)(wth1 + (size_t)128 * 128);
    int*   deg     = ints;                               // N
    int*   row_off = deg + N;                            // N+1 (sentinel)
    int*   cursor  = row_off + N + 1;                    // N
    int*   csr_src = cursor + N;                         // E
    int*   bsums   = csr_src + E;                        // <=256

    float* heads      = out + NF;
    float* e1_out     = out + 2 * NF;
    float* atten0_out = e1_out + (size_t)E * 4;
    float* atten1_out = atten0_out + E;

    // ---- prep: weight split + degree count (one launch) ----
    hipMemsetAsync(deg, 0, (size_t)N * sizeof(int), stream);
    const int wtot = 256 * 128 + 128 * 128;
    prep<<<(wtot + E + 255) / 256, 256, 0, stream>>>(W0, W1, wth0, wtl0, wth1,
                                                     dsts, deg, E);

    const int gemm_blocks = (N + 127) / 128;
    const int agg_blocks  = (N + 7) / 8;      // 2 nodes/wave, 4 waves/block
    const int edge_blocks = (E + 255) / 256;
    const int nb = (N + 1023) / 1024;

    // ---- layer 0: gemm + CSR block-scan in one launch ----
    gemm0_scan<<<gemm_blocks + nb, 256, 0, stream>>>(x, wth0, wtl0, feat16, al0, ar0,
                                                     el, er, N, 256, gemm_blocks,
                                                     deg, row_off, bsums, N);
    scan_fin<<<nb, 256, 0, stream>>>(row_off, bsums, cursor, deg, N, nb);
    fill_csr_edge0<<<edge_blocks, 256, 0, stream>>>(srcs, dsts, cursor, csr_src,
                                                    el, er, atten0_out, E);
    aggregate0<<<agg_blocks, 256, 0, stream>>>(row_off, csr_src, el, er,
                                               feat16, h1_16, N);

    // ---- layer 1 ----
    gemm_mfma1<<<gemm_blocks, 256, 0, stream>>>(h1_16, wth1, feat16, al1, ar1,
                                                el, er, N, 128);
    layer1_fused<<<agg_blocks + edge_blocks, 256, 0, stream>>>(
        row_off, csr_src, el, er, feat16, h1_16, out, heads,
        srcs, dsts, e1_out, atten1_out, agg_blocks, N, E);
}